// Round 6
// baseline (443.332 us; speedup 1.0000x reference)
//
#include <hip/hip_runtime.h>
#include <hip/hip_fp16.h>

typedef unsigned short u16;
typedef unsigned int   u32;
typedef __attribute__((ext_vector_type(8))) short short8;
typedef __attribute__((ext_vector_type(8))) unsigned short ushort8v;
typedef __attribute__((ext_vector_type(4))) float f32x4;

#define TPB 256

__device__ __forceinline__ float b2f(u16 u){ u32 x=((u32)u)<<16; return __uint_as_float(x); }
__device__ __forceinline__ u16 f2b(float f){ u32 x=__float_as_uint(f); u32 r=x+0x7FFFu+((x>>16)&1u); return (u16)(r>>16); }
__device__ __forceinline__ float lrelu(float x){ return x>0.f?x:0.2f*x; }
__device__ __forceinline__ float sigm(float x){ return 1.f/(1.f+__expf(-x)); }

__device__ __forceinline__ float4 ld4(const void* p, size_t i4, int isbf){
  if(isbf){
    ushort4 u=((const ushort4*)p)[i4];
    return make_float4(b2f(u.x),b2f(u.y),b2f(u.z),b2f(u.w));
  }
  return ((const float4*)p)[i4];
}
__device__ __forceinline__ float ld1(const void* p, size_t i, int isbf){
  return isbf ? b2f(((const u16*)p)[i]) : ((const float*)p)[i];
}

// ---------------- wire-dtype detection (flag=1 -> bf16 wire, 0 -> f32 wire) ----------------
__global__ void k_detect(const u16* __restrict__ w, int* __restrict__ flag){
  __shared__ int s[256];
  int t=threadIdx.x, sane=0;
  for(int i=t;i<512;i+=256){
    u16 u=w[i]; u32 e=(u>>7)&0xFFu;
    if((e>=103u&&e<=143u)||((u&0x7FFFu)==0u)) sane++;
  }
  s[t]=sane; __syncthreads();
  for(int o=128;o;o>>=1){ if(t<o) s[t]+=s[t+o]; __syncthreads(); }
  if(t==0) flag[0]=(s[0]>=480)?1:0;
}

// ---------------- graph build ----------------
__global__ void k_deg(const int* __restrict__ dst, int E, int N, int* __restrict__ deg){
  int e=blockIdx.x*blockDim.x+threadIdx.x; if(e>=E+N) return;
  int d=(e<E)?dst[e]:(e-E);
  d=min(max(d,0),N-1);
  atomicAdd(&deg[d],1);
}

__global__ void k_scan(const int* __restrict__ deg, int* __restrict__ rs,
                       int* __restrict__ counter, int n,
                       const int* __restrict__ aidx, int* __restrict__ ainv, int na){
  __shared__ int tmp[TPB];
  __shared__ int base;
  int i=blockIdx.x*TPB+threadIdx.x;
  if(i<na){ int a=aidx[i]; if(a>=0&&a<n) ainv[a]=i; }
  int v=(i<n)?deg[i]:0;
  tmp[threadIdx.x]=v; __syncthreads();
  for(int off=1;off<TPB;off<<=1){
    int t=(threadIdx.x>=off)?tmp[threadIdx.x-off]:0;
    __syncthreads();
    tmp[threadIdx.x]+=t;
    __syncthreads();
  }
  if(threadIdx.x==TPB-1) base=atomicAdd(counter,tmp[TPB-1]);
  __syncthreads();
  if(i<n) rs[i]=base+tmp[threadIdx.x]-v;
}

__global__ void k_fill(const int* __restrict__ src, const int* __restrict__ dst, int E, int N,
                       const int* __restrict__ rs, int* __restrict__ fill, int* __restrict__ col){
  int e=blockIdx.x*blockDim.x+threadIdx.x; if(e>=E+N) return;
  int d,s;
  if(e<E){ d=dst[e]; s=src[e]; } else { d=e-E; s=e-E; }
  d=min(max(d,0),N-1); s=min(max(s,0),N-1);
  int p=rs[d]+atomicAdd(&fill[d],1);
  col[p]=s;
}

// ---------------- W[256,256] -> WT = W^T as bf16 (z selects which weight) ----------------
__global__ __launch_bounds__(256) void k_trans(const void* __restrict__ Wa, u16* __restrict__ WTa,
                                               const void* __restrict__ Wb, u16* __restrict__ WTb,
                                               const int* __restrict__ flag){
  __shared__ float s[64][65];
  const void* W = blockIdx.z ? Wb : Wa;
  u16* WT = blockIdx.z ? WTb : WTa;
  const int isbf=flag[0];
  int tx=threadIdx.x&63, ty=threadIdx.x>>6;
  int k0=blockIdx.x*64, n0=blockIdx.y*64;
  #pragma unroll
  for(int i=0;i<64;i+=4)
    s[ty+i][tx]=ld1(W,(size_t)(k0+ty+i)*256+n0+tx,isbf);
  __syncthreads();
  #pragma unroll
  for(int i=0;i<64;i+=4)
    WT[(size_t)(n0+ty+i)*256+k0+tx]=f2b(s[tx][ty+i]);
}

// ---------------- MFMA GEMM: C[M,256] = A[M,256] @ B[256,256], BT = B^T bf16 ----------------
__global__ __launch_bounds__(256) void k_gemm(const void* __restrict__ A, const u16* __restrict__ BT,
                                              u16* __restrict__ C, int M,
                                              const int* __restrict__ flag, int amode){
  __shared__ short As[128*32];
  __shared__ short Bs[128*32];
  const int a_isbf = amode ? 1 : flag[0];
  const int t=threadIdx.x;
  const int lane=t&63, wv=t>>6;
  const int wm=wv>>1, wn=wv&1;
  const int m15=lane&15, kg=lane>>4;
  const int gm0=blockIdx.x*128, n0=blockIdx.y*128;
  f32x4 acc[4][4]={};
  for(int k0=0;k0<256;k0+=32){
    #pragma unroll
    for(int i=0;i<2;++i){
      int c=i*256+t;
      int r=c>>2, kq=c&3;
      int sw=(kq^((r>>1)&3))*8;
      int gr=gm0+r; gr=gr<M?gr:M-1;
      size_t ge=(size_t)gr*256+k0+kq*8;
      short8 av;
      if(a_isbf){
        av=*(const short8*)((const u16*)A+ge);
      }else{
        const float4* fp=(const float4*)((const float*)A+ge);
        float4 f0=fp[0], f1=fp[1];
        av[0]=(short)f2b(f0.x); av[1]=(short)f2b(f0.y); av[2]=(short)f2b(f0.z); av[3]=(short)f2b(f0.w);
        av[4]=(short)f2b(f1.x); av[5]=(short)f2b(f1.y); av[6]=(short)f2b(f1.z); av[7]=(short)f2b(f1.w);
      }
      *(short8*)&As[r*32+sw]=av;
      short8 bv=*(const short8*)(BT+(size_t)(n0+r)*256+k0+kq*8);
      *(short8*)&Bs[r*32+sw]=bv;
    }
    __syncthreads();
    short8 af[4], bf[4];
    #pragma unroll
    for(int mi=0;mi<4;++mi){
      int row=wm*64+mi*16+m15;
      af[mi]=*(const short8*)&As[row*32+((kg^((row>>1)&3)))*8];
    }
    #pragma unroll
    for(int ni=0;ni<4;++ni){
      int row=wn*64+ni*16+m15;
      bf[ni]=*(const short8*)&Bs[row*32+((kg^((row>>1)&3)))*8];
    }
    #pragma unroll
    for(int mi=0;mi<4;++mi)
      #pragma unroll
      for(int ni=0;ni<4;++ni)
        acc[mi][ni]=__builtin_amdgcn_mfma_f32_16x16x32_bf16(af[mi],bf[ni],acc[mi][ni],0,0,0);
    __syncthreads();
  }
  #pragma unroll
  for(int mi=0;mi<4;++mi){
    #pragma unroll
    for(int r=0;r<4;++r){
      int grow=gm0+wm*64+mi*16+kg*4+r;
      if(grow<M){
        #pragma unroll
        for(int ni=0;ni<4;++ni){
          int gcol=n0+wn*64+ni*16+m15;
          C[(size_t)grow*256+gcol]=f2b(acc[mi][ni][r]);
        }
      }
    }
  }
}

// ---------------- attention logits per node (xl internal bf16) ----------------
__global__ __launch_bounds__(256) void k_att(const u16* __restrict__ xl, const void* __restrict__ as_,
                                             const void* __restrict__ ad_, float* __restrict__ asrc,
                                             float* __restrict__ adst, int n,
                                             const int* __restrict__ flag){
  const int isbf=flag[0];
  int w=(blockIdx.x*256+threadIdx.x)>>6;
  int lane=threadIdx.x&63;
  if(w>=n) return;
  int ch=lane*4;
  ushort4 u=*(const ushort4*)(xl+(size_t)w*256+ch);
  float4 s=ld4(as_,ch>>2,isbf);
  float4 d=ld4(ad_,ch>>2,isbf);
  float x0=b2f(u.x),x1=b2f(u.y),x2=b2f(u.z),x3=b2f(u.w);
  float ps=x0*s.x+x1*s.y+x2*s.z+x3*s.w;
  float pd=x0*d.x+x1*d.y+x2*d.z+x3*d.w;
  for(int off=16;off;off>>=1){ ps+=__shfl_xor(ps,off); pd+=__shfl_xor(pd,off); }
  if((lane&31)==0){ int h=lane>>5; asrc[w*2+h]=ps; adst[w*2+h]=pd; }
}

// ---------------- per-edge softmax weights + per-dst denominators ----------------
__global__ __launch_bounds__(256) void k_alpha(const int* __restrict__ rs, const int* __restrict__ deg,
    const int* __restrict__ col, const float2* __restrict__ asrc2, const float2* __restrict__ adst2,
    u32* __restrict__ wpk, float2* __restrict__ rden, int n){
  int w=(blockIdx.x*256+threadIdx.x)>>6;
  int lane=threadIdx.x&63;
  if(w>=n) return;
  int s0=rs[w], cnt=deg[w];
  float2 ad=adst2[w];
  float sum0=0.f, sum1=0.f;
  for(int base=0;base<cnt;base+=64){
    int j=base+lane;
    if(j<cnt){
      int sv=col[s0+j];
      float2 a=asrc2[sv];
      float e0=fminf(lrelu(a.x+ad.x),11.f);   // clamp: keep exp finite in f16
      float e1=fminf(lrelu(a.y+ad.y),11.f);
      float w0=__expf(e0), w1=__expf(e1);
      sum0+=w0; sum1+=w1;
      __half2 p=__floats2half2_rn(w0,w1);
      wpk[s0+j]=*(u32*)&p;
    }
  }
  for(int off=32;off;off>>=1){ sum0+=__shfl_xor(sum0,off); sum1+=__shfl_xor(sum1,off); }
  if(lane==0) rden[w]=make_float2(1.f/(sum0+1e-16f),1.f/(sum1+1e-16f));
}

// ---------------- weighted aggregation: wave per dst, half-wave per edge ----------------
// Each half-wave (32 lanes x 16B) reads a full 512B xl row per edge slot;
// 4 slots/iter = 8 edges in flight. Branchless: invalid slots read row 0 with
// weight 0 (L1-hit, harmless). Halves merged once at the end via shfl_xor(32).
__global__ __launch_bounds__(256) void k_agg(const int* __restrict__ rs, const int* __restrict__ deg,
    const int* __restrict__ col, const u32* __restrict__ wpk, const float2* __restrict__ rden,
    const u16* __restrict__ xl, const void* __restrict__ bias,
    u16* __restrict__ hout, void* __restrict__ out, int ostride, int ocol,
    const int* __restrict__ ainv, int n, const int* __restrict__ flag){
  const int isbf=flag[0];
  int w=(blockIdx.x*blockDim.x+threadIdx.x)>>6;
  int lane=threadIdx.x&63;
  if(w>=n) return;
  const int half=lane>>5, sl=lane&31;
  const int ch=sl*8;          // 8 channels per lane (32 lanes cover 256)
  const int hh=sl>>4;         // head index for this lane's channels
  int s0=rs[w], cnt=deg[w];
  float acc[8]={};
  for(int j=0;j<cnt;j+=8){
    int sb[4]; u32 ap[4];
    #pragma unroll
    for(int u=0;u<4;++u){
      int e=j+u*2+half;
      bool v=e<cnt;
      sb[u]=v?col[s0+e]:0;
      ap[u]=v?wpk[s0+e]:0u;   // 0 bits -> half2(0,0) -> weight 0
    }
    ushort8v rr[4];
    #pragma unroll
    for(int u=0;u<4;++u)
      rr[u]=*(const ushort8v*)(xl+(size_t)sb[u]*256+ch);
    #pragma unroll
    for(int u=0;u<4;++u){
      __half2 p=*(__half2*)&ap[u];
      float wb=__half2float(hh?__high2half(p):__low2half(p));
      #pragma unroll
      for(int c=0;c<8;++c) acc[c]+=wb*b2f(rr[u][c]);
    }
  }
  #pragma unroll
  for(int c=0;c<8;++c) acc[c]+=__shfl_xor(acc[c],32);
  if(half==0){
    float2 rd=rden[w];
    float rh=hh?rd.y:rd.x;
    float4 b0=ld4(bias,ch>>2,isbf);
    float4 b1=ld4(bias,(ch>>2)+1,isbf);
    float r[8];
    r[0]=sigm(acc[0]*rh+b0.x); r[1]=sigm(acc[1]*rh+b0.y);
    r[2]=sigm(acc[2]*rh+b0.z); r[3]=sigm(acc[3]*rh+b0.w);
    r[4]=sigm(acc[4]*rh+b1.x); r[5]=sigm(acc[5]*rh+b1.y);
    r[6]=sigm(acc[6]*rh+b1.z); r[7]=sigm(acc[7]*rh+b1.w);
    ushort8v ov;
    #pragma unroll
    for(int c=0;c<8;++c) ov[c]=f2b(r[c]);
    if(hout) *(ushort8v*)(hout+(size_t)w*256+ch)=ov;
    int ar=ainv[w];
    if(ar>=0){
      size_t o=(size_t)ar*ostride+ocol+ch;
      if(isbf){
        *(ushort8v*)((u16*)out+o)=ov;
      }else{
        *(float4*)((float*)out+o)  =make_float4(r[0],r[1],r[2],r[3]);
        *(float4*)((float*)out+o+4)=make_float4(r[4],r[5],r[6],r[7]);
      }
    }
  }
}

extern "C" void kernel_launch(void* const* d_in, const int* in_sizes, int n_in,
                              void* d_out, int out_size, void* d_ws, size_t ws_size,
                              hipStream_t stream) {
  const void* x   = d_in[0];
  const int*  ei  = (const int*)d_in[1];
  const int*  aidx= (const int*)d_in[3];
  const void* W0  = d_in[4];
  const void* as0 = d_in[5];
  const void* ad0 = d_in[6];
  const void* b0  = d_in[7];
  const void* W1  = d_in[8];
  const void* as1 = d_in[9];
  const void* ad1 = d_in[10];
  const void* b1  = d_in[11];

  const int N  = in_sizes[0]/256;
  const int E  = in_sizes[1]/2;
  const int na = in_sizes[3];
  const int Et = E+N;

  char* ws=(char*)d_ws; size_t off=0;
  auto alloc=[&](size_t bytes)->void*{ void* p=ws+off; off+=(bytes+255)&~(size_t)255; return p; };
  int*   flg =(int*) alloc(256);
  u16*   xl  =(u16*) alloc((size_t)N*256*2);
  u16*   h1  =(u16*) alloc((size_t)N*256*2);
  u16*   WT0 =(u16*) alloc((size_t)256*256*2);
  u16*   WT1 =(u16*) alloc((size_t)256*256*2);
  float* asr =(float*)alloc((size_t)N*2*4);
  float* ads =(float*)alloc((size_t)N*2*4);
  char*  zbase=ws+off;
  int*   deg =(int*) alloc((size_t)N*4);
  int*   fill=(int*) alloc((size_t)N*4);
  int*   ctr =(int*) alloc(256);
  size_t zlen=(ws+off)-zbase;
  int*   rstp=(int*) alloc((size_t)N*4);
  int*   ainv=(int*) alloc((size_t)N*4);
  int*   col =(int*) alloc((size_t)Et*4);
  u32*   wpk =(u32*) alloc((size_t)Et*4);
  float2* rdn=(float2*)alloc((size_t)N*8);

  const int* esrc=ei;
  const int* edst=ei+E;

  hipMemsetAsync(zbase,0,zlen,stream);
  hipMemsetAsync(ainv,0xFF,(size_t)N*4,stream);

  k_detect<<<1,256,0,stream>>>((const u16*)W0,flg);
  k_deg  <<<(Et+255)/256,256,0,stream>>>(edst,E,N,deg);
  k_scan <<<(N+TPB-1)/TPB,TPB,0,stream>>>(deg,rstp,ctr,N,aidx,ainv,na);
  k_fill <<<(Et+255)/256,256,0,stream>>>(esrc,edst,E,N,rstp,fill,col);
  k_trans<<<dim3(4,4,2),256,0,stream>>>(W0,WT0,W1,WT1,flg);

  dim3 gg((N+127)/128,2);
  // layer 0
  k_gemm <<<gg,256,0,stream>>>(x,WT0,xl,N,flg,0);
  k_att  <<<(N+3)/4,256,0,stream>>>(xl,as0,ad0,asr,ads,N,flg);
  k_alpha<<<(N+3)/4,256,0,stream>>>(rstp,deg,col,(const float2*)asr,(const float2*)ads,wpk,rdn,N);
  k_agg  <<<(N+3)/4,256,0,stream>>>(rstp,deg,col,wpk,rdn,xl,b0,h1,d_out,512,0,ainv,N,flg);
  // layer 1
  k_gemm <<<gg,256,0,stream>>>(h1,WT1,xl,N,flg,1);
  k_att  <<<(N+3)/4,256,0,stream>>>(xl,as1,ad1,asr,ads,N,flg);
  k_alpha<<<(N+3)/4,256,0,stream>>>(rstp,deg,col,(const float2*)asr,(const float2*)ads,wpk,rdn,N);
  k_agg  <<<(N+3)/4,256,0,stream>>>(rstp,deg,col,wpk,rdn,xl,b1,(u16*)nullptr,d_out,512,256,ainv,N,flg);
}

// Round 7
// 427.358 us; speedup vs baseline: 1.0374x; 1.0374x over previous
//
#include <hip/hip_runtime.h>
#include <hip/hip_fp16.h>

typedef unsigned short u16;
typedef unsigned int   u32;
typedef __attribute__((ext_vector_type(8))) short short8;
typedef __attribute__((ext_vector_type(8))) unsigned short ushort8v;
typedef __attribute__((ext_vector_type(4))) float f32x4;

#define TPB 256

#define GLDS16(g,l) __builtin_amdgcn_global_load_lds( \
    (const __attribute__((address_space(1))) void*)(g), \
    (__attribute__((address_space(3))) void*)(l), 16, 0, 0)

__device__ __forceinline__ float b2f(u16 u){ u32 x=((u32)u)<<16; return __uint_as_float(x); }
__device__ __forceinline__ u16 f2b(float f){ u32 x=__float_as_uint(f); u32 r=x+0x7FFFu+((x>>16)&1u); return (u16)(r>>16); }
__device__ __forceinline__ float lrelu(float x){ return x>0.f?x:0.2f*x; }
__device__ __forceinline__ float sigm(float x){ return 1.f/(1.f+__expf(-x)); }

__device__ __forceinline__ float4 ld4(const void* p, size_t i4, int isbf){
  if(isbf){
    ushort4 u=((const ushort4*)p)[i4];
    return make_float4(b2f(u.x),b2f(u.y),b2f(u.z),b2f(u.w));
  }
  return ((const float4*)p)[i4];
}
__device__ __forceinline__ float ld1(const void* p, size_t i, int isbf){
  return isbf ? b2f(((const u16*)p)[i]) : ((const float*)p)[i];
}

// ---------------- wire-dtype detection (flag=1 -> bf16 wire, 0 -> f32 wire) ----------------
__global__ void k_detect(const u16* __restrict__ w, int* __restrict__ flag){
  __shared__ int s[256];
  int t=threadIdx.x, sane=0;
  for(int i=t;i<512;i+=256){
    u16 u=w[i]; u32 e=(u>>7)&0xFFu;
    if((e>=103u&&e<=143u)||((u&0x7FFFu)==0u)) sane++;
  }
  s[t]=sane; __syncthreads();
  for(int o=128;o;o>>=1){ if(t<o) s[t]+=s[t+o]; __syncthreads(); }
  if(t==0) flag[0]=(s[0]>=480)?1:0;
}

// ---------------- x (wire dtype) -> bf16, 8 elems/thread ----------------
__global__ __launch_bounds__(256) void k_x8(const void* __restrict__ X, u16* __restrict__ xb,
                                            int n8, const int* __restrict__ flag){
  int i=blockIdx.x*256+threadIdx.x; if(i>=n8) return;
  size_t e=(size_t)i*8;
  if(flag[0]){
    *(ushort8v*)(xb+e)=*(const ushort8v*)((const u16*)X+e);
  }else{
    const float4* fp=(const float4*)((const float*)X+e);
    float4 f0=fp[0], f1=fp[1];
    ushort8v o;
    o[0]=f2b(f0.x); o[1]=f2b(f0.y); o[2]=f2b(f0.z); o[3]=f2b(f0.w);
    o[4]=f2b(f1.x); o[5]=f2b(f1.y); o[6]=f2b(f1.z); o[7]=f2b(f1.w);
    *(ushort8v*)(xb+e)=o;
  }
}

// ---------------- graph build ----------------
__global__ void k_deg(const int* __restrict__ dst, int E, int N, int* __restrict__ deg){
  int e=blockIdx.x*blockDim.x+threadIdx.x; if(e>=E+N) return;
  int d=(e<E)?dst[e]:(e-E);
  d=min(max(d,0),N-1);
  atomicAdd(&deg[d],1);
}

__global__ void k_scan(const int* __restrict__ deg, int* __restrict__ rs,
                       int* __restrict__ counter, int n,
                       const int* __restrict__ aidx, int* __restrict__ ainv, int na){
  __shared__ int tmp[TPB];
  __shared__ int base;
  int i=blockIdx.x*TPB+threadIdx.x;
  if(i<na){ int a=aidx[i]; if(a>=0&&a<n) ainv[a]=i; }
  int v=(i<n)?deg[i]:0;
  tmp[threadIdx.x]=v; __syncthreads();
  for(int off=1;off<TPB;off<<=1){
    int t=(threadIdx.x>=off)?tmp[threadIdx.x-off]:0;
    __syncthreads();
    tmp[threadIdx.x]+=t;
    __syncthreads();
  }
  if(threadIdx.x==TPB-1) base=atomicAdd(counter,tmp[TPB-1]);
  __syncthreads();
  if(i<n) rs[i]=base+tmp[threadIdx.x]-v;
}

__global__ void k_fill(const int* __restrict__ src, const int* __restrict__ dst, int E, int N,
                       const int* __restrict__ rs, int* __restrict__ fill, int* __restrict__ col){
  int e=blockIdx.x*blockDim.x+threadIdx.x; if(e>=E+N) return;
  int d,s;
  if(e<E){ d=dst[e]; s=src[e]; } else { d=e-E; s=e-E; }
  d=min(max(d,0),N-1); s=min(max(s,0),N-1);
  int p=rs[d]+atomicAdd(&fill[d],1);
  col[p]=s;
}

// ---------------- W[256,256] -> WT = W^T as bf16 (z selects which weight) ----------------
__global__ __launch_bounds__(256) void k_trans(const void* __restrict__ Wa, u16* __restrict__ WTa,
                                               const void* __restrict__ Wb, u16* __restrict__ WTb,
                                               const int* __restrict__ flag){
  __shared__ float s[64][65];
  const void* W = blockIdx.z ? Wb : Wa;
  u16* WT = blockIdx.z ? WTb : WTa;
  const int isbf=flag[0];
  int tx=threadIdx.x&63, ty=threadIdx.x>>6;
  int k0=blockIdx.x*64, n0=blockIdx.y*64;
  #pragma unroll
  for(int i=0;i<64;i+=4)
    s[ty+i][tx]=ld1(W,(size_t)(k0+ty+i)*256+n0+tx,isbf);
  __syncthreads();
  #pragma unroll
  for(int i=0;i<64;i+=4)
    WT[(size_t)(n0+ty+i)*256+k0+tx]=f2b(s[tx][ty+i]);
}

// ---------------- MFMA GEMM: C[M,256] = A[M,256] @ B, A bf16, BT = B^T bf16 ----------------
// Staging via global_load_lds(16B): wave wv covers tile rows [wv*32,wv*32+32),
// 2 instrs per operand per k-step (lane -> row wv*32+j*16+lane/4, slot lane&3).
// XOR swizzle slot = kq ^ ((row>>1)&3) is realized on the GLOBAL side (per-lane
// kq), so LDS writes stay the HW-mandated linear lane*16B and frag ds_read_b128
// stays 2-way-conflict (free).
__global__ __launch_bounds__(256) void k_gemm(const u16* __restrict__ A, const u16* __restrict__ BT,
                                              u16* __restrict__ C, int M){
  __shared__ short As[128*32];
  __shared__ short Bs[128*32];
  const int t=threadIdx.x;
  const int lane=t&63, wv=t>>6;
  const int wm=wv>>1, wn=wv&1;
  const int m15=lane&15, kg=lane>>4;
  const int gm0=blockIdx.x*128, n0=blockIdx.y*128;
  // staging source addresses for this lane (2 chunks per operand)
  int r0=wv*32+(lane>>2), r1=r0+16;
  int slot=lane&3;
  int kq0=slot^((r0>>1)&3), kq1=slot^((r1>>1)&3);
  int ga0=gm0+r0; ga0=ga0<M?ga0:M-1;
  int ga1=gm0+r1; ga1=ga1<M?ga1:M-1;
  const u16* ap0=A+(size_t)ga0*256+kq0*8;
  const u16* ap1=A+(size_t)ga1*256+kq1*8;
  const u16* bp0=BT+(size_t)(n0+r0)*256+kq0*8;
  const u16* bp1=BT+(size_t)(n0+r1)*256+kq1*8;
  short* al0=As+(wv*32)*32;      // wave-uniform LDS bases (lane*16B appended by HW)
  short* al1=As+(wv*32+16)*32;
  short* bl0=Bs+(wv*32)*32;
  short* bl1=Bs+(wv*32+16)*32;
  f32x4 acc[4][4]={};
  for(int k0=0;k0<256;k0+=32){
    GLDS16(ap0+k0,al0); GLDS16(ap1+k0,al1);
    GLDS16(bp0+k0,bl0); GLDS16(bp1+k0,bl1);
    __syncthreads();
    short8 af[4], bf[4];
    #pragma unroll
    for(int mi=0;mi<4;++mi){
      int row=wm*64+mi*16+m15;
      af[mi]=*(const short8*)&As[row*32+((kg^((row>>1)&3)))*8];
    }
    #pragma unroll
    for(int ni=0;ni<4;++ni){
      int row=wn*64+ni*16+m15;
      bf[ni]=*(const short8*)&Bs[row*32+((kg^((row>>1)&3)))*8];
    }
    #pragma unroll
    for(int mi=0;mi<4;++mi)
      #pragma unroll
      for(int ni=0;ni<4;++ni)
        acc[mi][ni]=__builtin_amdgcn_mfma_f32_16x16x32_bf16(af[mi],bf[ni],acc[mi][ni],0,0,0);
    __syncthreads();
  }
  #pragma unroll
  for(int mi=0;mi<4;++mi){
    #pragma unroll
    for(int r=0;r<4;++r){
      int grow=gm0+wm*64+mi*16+kg*4+r;
      if(grow<M){
        #pragma unroll
        for(int ni=0;ni<4;++ni){
          int gcol=n0+wn*64+ni*16+m15;
          C[(size_t)grow*256+gcol]=f2b(acc[mi][ni][r]);
        }
      }
    }
  }
}

// ---------------- attention logits per node (xl internal bf16) ----------------
__global__ __launch_bounds__(256) void k_att(const u16* __restrict__ xl, const void* __restrict__ as_,
                                             const void* __restrict__ ad_, float* __restrict__ asrc,
                                             float* __restrict__ adst, int n,
                                             const int* __restrict__ flag){
  const int isbf=flag[0];
  int w=(blockIdx.x*256+threadIdx.x)>>6;
  int lane=threadIdx.x&63;
  if(w>=n) return;
  int ch=lane*4;
  ushort4 u=*(const ushort4*)(xl+(size_t)w*256+ch);
  float4 s=ld4(as_,ch>>2,isbf);
  float4 d=ld4(ad_,ch>>2,isbf);
  float x0=b2f(u.x),x1=b2f(u.y),x2=b2f(u.z),x3=b2f(u.w);
  float ps=x0*s.x+x1*s.y+x2*s.z+x3*s.w;
  float pd=x0*d.x+x1*d.y+x2*d.z+x3*d.w;
  for(int off=16;off;off>>=1){ ps+=__shfl_xor(ps,off); pd+=__shfl_xor(pd,off); }
  if((lane&31)==0){ int h=lane>>5; asrc[w*2+h]=ps; adst[w*2+h]=pd; }
}

// ---------------- per-edge softmax weights + per-dst denominators ----------------
__global__ __launch_bounds__(256) void k_alpha(const int* __restrict__ rs, const int* __restrict__ deg,
    const int* __restrict__ col, const float2* __restrict__ asrc2, const float2* __restrict__ adst2,
    u32* __restrict__ wpk, float2* __restrict__ rden, int n){
  int w=(blockIdx.x*256+threadIdx.x)>>6;
  int lane=threadIdx.x&63;
  if(w>=n) return;
  int s0=rs[w], cnt=deg[w];
  float2 ad=adst2[w];
  float sum0=0.f, sum1=0.f;
  for(int base=0;base<cnt;base+=64){
    int j=base+lane;
    if(j<cnt){
      int sv=col[s0+j];
      float2 a=asrc2[sv];
      float e0=fminf(lrelu(a.x+ad.x),11.f);
      float e1=fminf(lrelu(a.y+ad.y),11.f);
      float w0=__expf(e0), w1=__expf(e1);
      sum0+=w0; sum1+=w1;
      __half2 p=__floats2half2_rn(w0,w1);
      wpk[s0+j]=*(u32*)&p;
    }
  }
  for(int off=32;off;off>>=1){ sum0+=__shfl_xor(sum0,off); sum1+=__shfl_xor(sum1,off); }
  if(lane==0) rden[w]=make_float2(1.f/(sum0+1e-16f),1.f/(sum1+1e-16f));
}

// ---------------- weighted aggregation: wave per dst (round-5 form, unroll 8) ----------------
__global__ __launch_bounds__(256) void k_agg(const int* __restrict__ rs, const int* __restrict__ deg,
    const int* __restrict__ col, const u32* __restrict__ wpk, const float2* __restrict__ rden,
    const u16* __restrict__ xl, const void* __restrict__ bias,
    u16* __restrict__ hout, void* __restrict__ out, int ostride, int ocol,
    const int* __restrict__ ainv, int n, const int* __restrict__ flag){
  const int isbf=flag[0];
  int w=(blockIdx.x*blockDim.x+threadIdx.x)>>6;
  int lane=threadIdx.x&63;
  if(w>=n) return;
  int s0=rs[w], cnt=deg[w];
  int ch=lane*4, h=ch>>7;
  float4 acc=make_float4(0.f,0.f,0.f,0.f);
  int j=0;
  for(; j+8<=cnt; j+=8){
    int sb[8]; u32 ap[8];
    #pragma unroll
    for(int u=0;u<8;++u){ sb[u]=col[s0+j+u]; ap[u]=wpk[s0+j+u]; }
    ushort4 r[8];
    #pragma unroll
    for(int u=0;u<8;++u) r[u]=*(const ushort4*)(xl+(size_t)sb[u]*256+ch);
    #pragma unroll
    for(int u=0;u<8;++u){
      __half2 p=*(__half2*)&ap[u];
      float wb=__half2float(h?__high2half(p):__low2half(p));
      acc.x+=wb*b2f(r[u].x); acc.y+=wb*b2f(r[u].y);
      acc.z+=wb*b2f(r[u].z); acc.w+=wb*b2f(r[u].w);
    }
  }
  for(; j<cnt; ++j){
    int sb=col[s0+j]; u32 ap=wpk[s0+j];
    ushort4 r=*(const ushort4*)(xl+(size_t)sb*256+ch);
    __half2 p=*(__half2*)&ap;
    float wb=__half2float(h?__high2half(p):__low2half(p));
    acc.x+=wb*b2f(r.x); acc.y+=wb*b2f(r.y);
    acc.z+=wb*b2f(r.z); acc.w+=wb*b2f(r.w);
  }
  float2 rd=rden[w];
  float rh=h?rd.y:rd.x;
  float4 bv=ld4(bias,ch>>2,isbf);
  float r0=sigm(acc.x*rh+bv.x);
  float r1=sigm(acc.y*rh+bv.y);
  float r2=sigm(acc.z*rh+bv.z);
  float r3=sigm(acc.w*rh+bv.w);
  if(hout){
    ushort4 ov; ov.x=f2b(r0); ov.y=f2b(r1); ov.z=f2b(r2); ov.w=f2b(r3);
    *(ushort4*)(hout+(size_t)w*256+ch)=ov;
  }
  int ar=ainv[w];
  if(ar>=0){
    size_t o=(size_t)ar*ostride+ocol+ch;
    if(isbf){
      ushort4 ov; ov.x=f2b(r0); ov.y=f2b(r1); ov.z=f2b(r2); ov.w=f2b(r3);
      *(ushort4*)((u16*)out+o)=ov;
    }else{
      *(float4*)((float*)out+o)=make_float4(r0,r1,r2,r3);
    }
  }
}

extern "C" void kernel_launch(void* const* d_in, const int* in_sizes, int n_in,
                              void* d_out, int out_size, void* d_ws, size_t ws_size,
                              hipStream_t stream) {
  const void* x   = d_in[0];
  const int*  ei  = (const int*)d_in[1];
  const int*  aidx= (const int*)d_in[3];
  const void* W0  = d_in[4];
  const void* as0 = d_in[5];
  const void* ad0 = d_in[6];
  const void* b0  = d_in[7];
  const void* W1  = d_in[8];
  const void* as1 = d_in[9];
  const void* ad1 = d_in[10];
  const void* b1  = d_in[11];

  const int N  = in_sizes[0]/256;
  const int E  = in_sizes[1]/2;
  const int na = in_sizes[3];
  const int Et = E+N;

  char* ws=(char*)d_ws; size_t off=0;
  auto alloc=[&](size_t bytes)->void*{ void* p=ws+off; off+=(bytes+255)&~(size_t)255; return p; };
  int*   flg =(int*) alloc(256);
  u16*   xl  =(u16*) alloc((size_t)N*256*2);
  u16*   h1  =(u16*) alloc((size_t)N*256*2);   // doubles as xb (x in bf16): dead before k_agg writes h1
  u16*   WT0 =(u16*) alloc((size_t)256*256*2);
  u16*   WT1 =(u16*) alloc((size_t)256*256*2);
  float* asr =(float*)alloc((size_t)N*2*4);
  float* ads =(float*)alloc((size_t)N*2*4);
  char*  zbase=ws+off;
  int*   deg =(int*) alloc((size_t)N*4);
  int*   fill=(int*) alloc((size_t)N*4);
  int*   ctr =(int*) alloc(256);
  size_t zlen=(ws+off)-zbase;
  int*   rstp=(int*) alloc((size_t)N*4);
  int*   ainv=(int*) alloc((size_t)N*4);
  int*   col =(int*) alloc((size_t)Et*4);
  u32*   wpk =(u32*) alloc((size_t)Et*4);
  float2* rdn=(float2*)alloc((size_t)N*8);

  u16* xb = h1;   // alias (see above)

  const int* esrc=ei;
  const int* edst=ei+E;

  hipMemsetAsync(zbase,0,zlen,stream);
  hipMemsetAsync(ainv,0xFF,(size_t)N*4,stream);

  k_detect<<<1,256,0,stream>>>((const u16*)W0,flg);
  k_deg  <<<(Et+255)/256,256,0,stream>>>(edst,E,N,deg);
  k_scan <<<(N+TPB-1)/TPB,TPB,0,stream>>>(deg,rstp,ctr,N,aidx,ainv,na);
  k_fill <<<(Et+255)/256,256,0,stream>>>(esrc,edst,E,N,rstp,fill,col);
  k_trans<<<dim3(4,4,2),256,0,stream>>>(W0,WT0,W1,WT1,flg);
  k_x8   <<<(N*32+255)/256,256,0,stream>>>(x,xb,N*32,flg);

  dim3 gg((N+127)/128,2);
  // layer 0
  k_gemm <<<gg,256,0,stream>>>(xb,WT0,xl,N);
  k_att  <<<(N+3)/4,256,0,stream>>>(xl,as0,ad0,asr,ads,N,flg);
  k_alpha<<<(N+3)/4,256,0,stream>>>(rstp,deg,col,(const float2*)asr,(const float2*)ads,wpk,rdn,N);
  k_agg  <<<(N+3)/4,256,0,stream>>>(rstp,deg,col,wpk,rdn,xl,b0,h1,d_out,512,0,ainv,N,flg);
  // layer 1
  k_gemm <<<gg,256,0,stream>>>(h1,WT1,xl,N);
  k_att  <<<(N+3)/4,256,0,stream>>>(xl,as1,ad1,asr,ads,N,flg);
  k_alpha<<<(N+3)/4,256,0,stream>>>(rstp,deg,col,(const float2*)asr,(const float2*)ads,wpk,rdn,N);
  k_agg  <<<(N+3)/4,256,0,stream>>>(rstp,deg,col,wpk,rdn,xl,b1,(u16*)nullptr,d_out,512,256,ainv,N,flg);
}

// Round 8
// 425.519 us; speedup vs baseline: 1.0419x; 1.0043x over previous
//
#include <hip/hip_runtime.h>
#include <hip/hip_fp16.h>

typedef unsigned short u16;
typedef unsigned int   u32;
typedef __attribute__((ext_vector_type(8))) short short8;
typedef __attribute__((ext_vector_type(8))) unsigned short ushort8v;
typedef __attribute__((ext_vector_type(4))) float f32x4;

#define TPB 256

#define GLDS16(g,l) __builtin_amdgcn_global_load_lds( \
    (const __attribute__((address_space(1))) void*)(g), \
    (__attribute__((address_space(3))) void*)(l), 16, 0, 0)

__device__ __forceinline__ float b2f(u16 u){ u32 x=((u32)u)<<16; return __uint_as_float(x); }
__device__ __forceinline__ u16 f2b(float f){ u32 x=__float_as_uint(f); u32 r=x+0x7FFFu+((x>>16)&1u); return (u16)(r>>16); }
__device__ __forceinline__ float lrelu(float x){ return x>0.f?x:0.2f*x; }
__device__ __forceinline__ float sigm(float x){ return 1.f/(1.f+__expf(-x)); }

__device__ __forceinline__ float4 ld4(const void* p, size_t i4, int isbf){
  if(isbf){
    ushort4 u=((const ushort4*)p)[i4];
    return make_float4(b2f(u.x),b2f(u.y),b2f(u.z),b2f(u.w));
  }
  return ((const float4*)p)[i4];
}
__device__ __forceinline__ float ld1(const void* p, size_t i, int isbf){
  return isbf ? b2f(((const u16*)p)[i]) : ((const float*)p)[i];
}

// ---------------- wire-dtype detection (flag=1 -> bf16 wire, 0 -> f32 wire) ----------------
__global__ void k_detect(const u16* __restrict__ w, int* __restrict__ flag){
  __shared__ int s[256];
  int t=threadIdx.x, sane=0;
  for(int i=t;i<512;i+=256){
    u16 u=w[i]; u32 e=(u>>7)&0xFFu;
    if((e>=103u&&e<=143u)||((u&0x7FFFu)==0u)) sane++;
  }
  s[t]=sane; __syncthreads();
  for(int o=128;o;o>>=1){ if(t<o) s[t]+=s[t+o]; __syncthreads(); }
  if(t==0) flag[0]=(s[0]>=480)?1:0;
}

// ---------------- x (wire dtype) -> bf16, 8 elems/thread ----------------
__global__ __launch_bounds__(256) void k_x8(const void* __restrict__ X, u16* __restrict__ xb,
                                            int n8, const int* __restrict__ flag){
  int i=blockIdx.x*256+threadIdx.x; if(i>=n8) return;
  size_t e=(size_t)i*8;
  if(flag[0]){
    *(ushort8v*)(xb+e)=*(const ushort8v*)((const u16*)X+e);
  }else{
    const float4* fp=(const float4*)((const float*)X+e);
    float4 f0=fp[0], f1=fp[1];
    ushort8v o;
    o[0]=f2b(f0.x); o[1]=f2b(f0.y); o[2]=f2b(f0.z); o[3]=f2b(f0.w);
    o[4]=f2b(f1.x); o[5]=f2b(f1.y); o[6]=f2b(f1.z); o[7]=f2b(f1.w);
    *(ushort8v*)(xb+e)=o;
  }
}

// ---------------- graph build ----------------
__global__ void k_deg(const int* __restrict__ dst, int E, int N, int* __restrict__ deg){
  int e=blockIdx.x*blockDim.x+threadIdx.x; if(e>=E+N) return;
  int d=(e<E)?dst[e]:(e-E);
  d=min(max(d,0),N-1);
  atomicAdd(&deg[d],1);
}

__global__ void k_scan(const int* __restrict__ deg, int* __restrict__ rs,
                       int* __restrict__ counter, int n,
                       const int* __restrict__ aidx, int* __restrict__ ainv, int na){
  __shared__ int tmp[TPB];
  __shared__ int base;
  int i=blockIdx.x*TPB+threadIdx.x;
  if(i<na){ int a=aidx[i]; if(a>=0&&a<n) ainv[a]=i; }
  int v=(i<n)?deg[i]:0;
  tmp[threadIdx.x]=v; __syncthreads();
  for(int off=1;off<TPB;off<<=1){
    int t=(threadIdx.x>=off)?tmp[threadIdx.x-off]:0;
    __syncthreads();
    tmp[threadIdx.x]+=t;
    __syncthreads();
  }
  if(threadIdx.x==TPB-1) base=atomicAdd(counter,tmp[TPB-1]);
  __syncthreads();
  if(i<n) rs[i]=base+tmp[threadIdx.x]-v;
}

__global__ void k_fill(const int* __restrict__ src, const int* __restrict__ dst, int E, int N,
                       const int* __restrict__ rs, int* __restrict__ fill, int* __restrict__ col){
  int e=blockIdx.x*blockDim.x+threadIdx.x; if(e>=E+N) return;
  int d,s;
  if(e<E){ d=dst[e]; s=src[e]; } else { d=e-E; s=e-E; }
  d=min(max(d,0),N-1); s=min(max(s,0),N-1);
  int p=rs[d]+atomicAdd(&fill[d],1);
  col[p]=s;
}

// ---------------- W[256,256] -> WT = W^T as bf16 (z selects which weight) ----------------
__global__ __launch_bounds__(256) void k_trans(const void* __restrict__ Wa, u16* __restrict__ WTa,
                                               const void* __restrict__ Wb, u16* __restrict__ WTb,
                                               const int* __restrict__ flag){
  __shared__ float s[64][65];
  const void* W = blockIdx.z ? Wb : Wa;
  u16* WT = blockIdx.z ? WTb : WTa;
  const int isbf=flag[0];
  int tx=threadIdx.x&63, ty=threadIdx.x>>6;
  int k0=blockIdx.x*64, n0=blockIdx.y*64;
  #pragma unroll
  for(int i=0;i<64;i+=4)
    s[ty+i][tx]=ld1(W,(size_t)(k0+ty+i)*256+n0+tx,isbf);
  __syncthreads();
  #pragma unroll
  for(int i=0;i<64;i+=4)
    WT[(size_t)(n0+ty+i)*256+k0+tx]=f2b(s[tx][ty+i]);
}

// ---------------- MFMA GEMM: C[M,256] = A[M,256] @ B, A bf16, BT = B^T bf16 ----------------
__global__ __launch_bounds__(256) void k_gemm(const u16* __restrict__ A, const u16* __restrict__ BT,
                                              u16* __restrict__ C, int M){
  __shared__ short As[128*32];
  __shared__ short Bs[128*32];
  const int t=threadIdx.x;
  const int lane=t&63, wv=t>>6;
  const int wm=wv>>1, wn=wv&1;
  const int m15=lane&15, kg=lane>>4;
  const int gm0=blockIdx.x*128, n0=blockIdx.y*128;
  int r0=wv*32+(lane>>2), r1=r0+16;
  int slot=lane&3;
  int kq0=slot^((r0>>1)&3), kq1=slot^((r1>>1)&3);
  int ga0=gm0+r0; ga0=ga0<M?ga0:M-1;
  int ga1=gm0+r1; ga1=ga1<M?ga1:M-1;
  const u16* ap0=A+(size_t)ga0*256+kq0*8;
  const u16* ap1=A+(size_t)ga1*256+kq1*8;
  const u16* bp0=BT+(size_t)(n0+r0)*256+kq0*8;
  const u16* bp1=BT+(size_t)(n0+r1)*256+kq1*8;
  short* al0=As+(wv*32)*32;
  short* al1=As+(wv*32+16)*32;
  short* bl0=Bs+(wv*32)*32;
  short* bl1=Bs+(wv*32+16)*32;
  f32x4 acc[4][4]={};
  for(int k0=0;k0<256;k0+=32){
    GLDS16(ap0+k0,al0); GLDS16(ap1+k0,al1);
    GLDS16(bp0+k0,bl0); GLDS16(bp1+k0,bl1);
    __syncthreads();
    short8 af[4], bf[4];
    #pragma unroll
    for(int mi=0;mi<4;++mi){
      int row=wm*64+mi*16+m15;
      af[mi]=*(const short8*)&As[row*32+((kg^((row>>1)&3)))*8];
    }
    #pragma unroll
    for(int ni=0;ni<4;++ni){
      int row=wn*64+ni*16+m15;
      bf[ni]=*(const short8*)&Bs[row*32+((kg^((row>>1)&3)))*8];
    }
    #pragma unroll
    for(int mi=0;mi<4;++mi)
      #pragma unroll
      for(int ni=0;ni<4;++ni)
        acc[mi][ni]=__builtin_amdgcn_mfma_f32_16x16x32_bf16(af[mi],bf[ni],acc[mi][ni],0,0,0);
    __syncthreads();
  }
  #pragma unroll
  for(int mi=0;mi<4;++mi){
    #pragma unroll
    for(int r=0;r<4;++r){
      int grow=gm0+wm*64+mi*16+kg*4+r;
      if(grow<M){
        #pragma unroll
        for(int ni=0;ni<4;++ni){
          int gcol=n0+wn*64+ni*16+m15;
          C[(size_t)grow*256+gcol]=f2b(acc[mi][ni][r]);
        }
      }
    }
  }
}

// ---------------- attention logits per node (xl internal bf16) ----------------
__global__ __launch_bounds__(256) void k_att(const u16* __restrict__ xl, const void* __restrict__ as_,
                                             const void* __restrict__ ad_, float* __restrict__ asrc,
                                             float* __restrict__ adst, int n,
                                             const int* __restrict__ flag){
  const int isbf=flag[0];
  int w=(blockIdx.x*256+threadIdx.x)>>6;
  int lane=threadIdx.x&63;
  if(w>=n) return;
  int ch=lane*4;
  ushort4 u=*(const ushort4*)(xl+(size_t)w*256+ch);
  float4 s=ld4(as_,ch>>2,isbf);
  float4 d=ld4(ad_,ch>>2,isbf);
  float x0=b2f(u.x),x1=b2f(u.y),x2=b2f(u.z),x3=b2f(u.w);
  float ps=x0*s.x+x1*s.y+x2*s.z+x3*s.w;
  float pd=x0*d.x+x1*d.y+x2*d.z+x3*d.w;
  for(int off=16;off;off>>=1){ ps+=__shfl_xor(ps,off); pd+=__shfl_xor(pd,off); }
  if((lane&31)==0){ int h=lane>>5; asrc[w*2+h]=ps; adst[w*2+h]=pd; }
}

// ---------------- fused softmax + weighted aggregation, one wave per dst ----------------
// Edge weights computed inline, redundantly in every lane (col/asrc addresses are
// wave-uniform -> scalar/broadcast loads; exp is VALU, which has headroom).
// Denominator accumulated redundantly per lane -> no cross-lane ops at all.
__global__ __launch_bounds__(256) void k_agg(const int* __restrict__ rs, const int* __restrict__ deg,
    const int* __restrict__ col, const float2* __restrict__ asrc2, const float2* __restrict__ adst2,
    const u16* __restrict__ xl, const void* __restrict__ bias,
    u16* __restrict__ hout, void* __restrict__ out, int ostride, int ocol,
    const int* __restrict__ ainv, int n, const int* __restrict__ flag){
  const int isbf=flag[0];
  int w=(blockIdx.x*blockDim.x+threadIdx.x)>>6;
  int lane=threadIdx.x&63;
  if(w>=n) return;
  int s0=rs[w], cnt=deg[w];
  float2 ad=adst2[w];
  int ch=lane*4, h=ch>>7;
  float4 acc=make_float4(0.f,0.f,0.f,0.f);
  float sum0=0.f, sum1=0.f;
  int j=0;
  for(; j+8<=cnt; j+=8){
    int sb[8];
    #pragma unroll
    for(int u=0;u<8;++u) sb[u]=col[s0+j+u];
    float2 av[8];
    #pragma unroll
    for(int u=0;u<8;++u) av[u]=asrc2[sb[u]];
    ushort4 r[8];
    #pragma unroll
    for(int u=0;u<8;++u) r[u]=*(const ushort4*)(xl+(size_t)sb[u]*256+ch);
    #pragma unroll
    for(int u=0;u<8;++u){
      float w0=__expf(fminf(lrelu(av[u].x+ad.x),30.f));
      float w1=__expf(fminf(lrelu(av[u].y+ad.y),30.f));
      sum0+=w0; sum1+=w1;
      float wb=h?w1:w0;
      acc.x+=wb*b2f(r[u].x); acc.y+=wb*b2f(r[u].y);
      acc.z+=wb*b2f(r[u].z); acc.w+=wb*b2f(r[u].w);
    }
  }
  for(; j<cnt; ++j){
    int sb=col[s0+j];
    float2 a=asrc2[sb];
    ushort4 r=*(const ushort4*)(xl+(size_t)sb*256+ch);
    float w0=__expf(fminf(lrelu(a.x+ad.x),30.f));
    float w1=__expf(fminf(lrelu(a.y+ad.y),30.f));
    sum0+=w0; sum1+=w1;
    float wb=h?w1:w0;
    acc.x+=wb*b2f(r.x); acc.y+=wb*b2f(r.y);
    acc.z+=wb*b2f(r.z); acc.w+=wb*b2f(r.w);
  }
  float rh=1.f/((h?sum1:sum0)+1e-16f);
  float4 bv=ld4(bias,ch>>2,isbf);
  float r0=sigm(acc.x*rh+bv.x);
  float r1=sigm(acc.y*rh+bv.y);
  float r2=sigm(acc.z*rh+bv.z);
  float r3=sigm(acc.w*rh+bv.w);
  if(hout){
    ushort4 ov; ov.x=f2b(r0); ov.y=f2b(r1); ov.z=f2b(r2); ov.w=f2b(r3);
    *(ushort4*)(hout+(size_t)w*256+ch)=ov;
  }
  int ar=ainv[w];
  if(ar>=0){
    size_t o=(size_t)ar*ostride+ocol+ch;
    if(isbf){
      ushort4 ov; ov.x=f2b(r0); ov.y=f2b(r1); ov.z=f2b(r2); ov.w=f2b(r3);
      *(ushort4*)((u16*)out+o)=ov;
    }else{
      *(float4*)((float*)out+o)=make_float4(r0,r1,r2,r3);
    }
  }
}

extern "C" void kernel_launch(void* const* d_in, const int* in_sizes, int n_in,
                              void* d_out, int out_size, void* d_ws, size_t ws_size,
                              hipStream_t stream) {
  const void* x   = d_in[0];
  const int*  ei  = (const int*)d_in[1];
  const int*  aidx= (const int*)d_in[3];
  const void* W0  = d_in[4];
  const void* as0 = d_in[5];
  const void* ad0 = d_in[6];
  const void* b0  = d_in[7];
  const void* W1  = d_in[8];
  const void* as1 = d_in[9];
  const void* ad1 = d_in[10];
  const void* b1  = d_in[11];

  const int N  = in_sizes[0]/256;
  const int E  = in_sizes[1]/2;
  const int na = in_sizes[3];
  const int Et = E+N;

  char* ws=(char*)d_ws; size_t off=0;
  auto alloc=[&](size_t bytes)->void*{ void* p=ws+off; off+=(bytes+255)&~(size_t)255; return p; };
  int*   flg =(int*) alloc(256);
  u16*   xl  =(u16*) alloc((size_t)N*256*2);
  u16*   h1  =(u16*) alloc((size_t)N*256*2);   // doubles as xb (x in bf16): dead before k_agg writes h1
  u16*   WT0 =(u16*) alloc((size_t)256*256*2);
  u16*   WT1 =(u16*) alloc((size_t)256*256*2);
  float* asr =(float*)alloc((size_t)N*2*4);
  float* ads =(float*)alloc((size_t)N*2*4);
  char*  zbase=ws+off;
  int*   deg =(int*) alloc((size_t)N*4);
  int*   fill=(int*) alloc((size_t)N*4);
  int*   ctr =(int*) alloc(256);
  size_t zlen=(ws+off)-zbase;
  int*   rstp=(int*) alloc((size_t)N*4);
  int*   ainv=(int*) alloc((size_t)N*4);
  int*   col =(int*) alloc((size_t)Et*4);

  u16* xb = h1;   // alias (see above)

  const int* esrc=ei;
  const int* edst=ei+E;

  hipMemsetAsync(zbase,0,zlen,stream);
  hipMemsetAsync(ainv,0xFF,(size_t)N*4,stream);

  k_detect<<<1,256,0,stream>>>((const u16*)W0,flg);
  k_deg  <<<(Et+255)/256,256,0,stream>>>(edst,E,N,deg);
  k_scan <<<(N+TPB-1)/TPB,TPB,0,stream>>>(deg,rstp,ctr,N,aidx,ainv,na);
  k_fill <<<(Et+255)/256,256,0,stream>>>(esrc,edst,E,N,rstp,fill,col);
  k_trans<<<dim3(4,4,2),256,0,stream>>>(W0,WT0,W1,WT1,flg);
  k_x8   <<<(N*32+255)/256,256,0,stream>>>(x,xb,N*32,flg);

  dim3 gg((N+127)/128,2);
  // layer 0
  k_gemm <<<gg,256,0,stream>>>(xb,WT0,xl,N);
  k_att  <<<(N+3)/4,256,0,stream>>>(xl,as0,ad0,asr,ads,N,flg);
  k_agg  <<<(N+3)/4,256,0,stream>>>(rstp,deg,col,(const float2*)asr,(const float2*)ads,xl,b0,h1,d_out,512,0,ainv,N,flg);
  // layer 1
  k_gemm <<<gg,256,0,stream>>>(h1,WT1,xl,N);
  k_att  <<<(N+3)/4,256,0,stream>>>(xl,as1,ad1,asr,ads,N,flg);
  k_agg  <<<(N+3)/4,256,0,stream>>>(rstp,deg,col,(const float2*)asr,(const float2*)ads,xl,b1,(u16*)nullptr,d_out,512,256,ainv,N,flg);
}

// Round 10
// 395.094 us; speedup vs baseline: 1.1221x; 1.0770x over previous
//
#include <hip/hip_runtime.h>
#include <hip/hip_fp16.h>

typedef unsigned short u16;
typedef unsigned int   u32;
typedef unsigned char  u8;
typedef __attribute__((ext_vector_type(8))) short short8;
typedef __attribute__((ext_vector_type(8))) unsigned short ushort8v;
typedef __attribute__((ext_vector_type(4))) float f32x4;

#define TPB 256

#define GLDS16(g,l) __builtin_amdgcn_global_load_lds( \
    (const __attribute__((address_space(1))) void*)(g), \
    (__attribute__((address_space(3))) void*)(l), 16, 0, 0)

__device__ __forceinline__ float b2f(u16 u){ u32 x=((u32)u)<<16; return __uint_as_float(x); }
__device__ __forceinline__ u16 f2b(float f){ u32 x=__float_as_uint(f); u32 r=x+0x7FFFu+((x>>16)&1u); return (u16)(r>>16); }
__device__ __forceinline__ float lrelu(float x){ return x>0.f?x:0.2f*x; }
__device__ __forceinline__ float sigm(float x){ return 1.f/(1.f+__expf(-x)); }

__device__ __forceinline__ float4 ld4(const void* p, size_t i4, int isbf){
  if(isbf){
    ushort4 u=((const ushort4*)p)[i4];
    return make_float4(b2f(u.x),b2f(u.y),b2f(u.z),b2f(u.w));
  }
  return ((const float4*)p)[i4];
}
__device__ __forceinline__ float ld1(const void* p, size_t i, int isbf){
  return isbf ? b2f(((const u16*)p)[i]) : ((const float*)p)[i];
}

// ---------------- wire-dtype detection (flag=1 -> bf16 wire, 0 -> f32 wire) ----------------
__global__ void k_detect(const u16* __restrict__ w, int* __restrict__ flag){
  __shared__ int s[256];
  int t=threadIdx.x, sane=0;
  for(int i=t;i<512;i+=256){
    u16 u=w[i]; u32 e=(u>>7)&0xFFu;
    if((e>=103u&&e<=143u)||((u&0x7FFFu)==0u)) sane++;
  }
  s[t]=sane; __syncthreads();
  for(int o=128;o;o>>=1){ if(t<o) s[t]+=s[t+o]; __syncthreads(); }
  if(t==0) flag[0]=(s[0]>=480)?1:0;
}

// ---------------- x (wire dtype) -> bf16, 8 elems/thread ----------------
__global__ __launch_bounds__(256) void k_x8(const void* __restrict__ X, u16* __restrict__ xb,
                                            int n8, const int* __restrict__ flag){
  int i=blockIdx.x*256+threadIdx.x; if(i>=n8) return;
  size_t e=(size_t)i*8;
  if(flag[0]){
    *(ushort8v*)(xb+e)=*(const ushort8v*)((const u16*)X+e);
  }else{
    const float4* fp=(const float4*)((const float*)X+e);
    float4 f0=fp[0], f1=fp[1];
    ushort8v o;
    o[0]=f2b(f0.x); o[1]=f2b(f0.y); o[2]=f2b(f0.z); o[3]=f2b(f0.w);
    o[4]=f2b(f1.x); o[5]=f2b(f1.y); o[6]=f2b(f1.z); o[7]=f2b(f1.w);
    *(ushort8v*)(xb+e)=o;
  }
}

// ---------------- graph build ----------------
__global__ void k_deg(const int* __restrict__ dst, int E, int N, int* __restrict__ deg){
  int e=blockIdx.x*blockDim.x+threadIdx.x; if(e>=E+N) return;
  int d=(e<E)?dst[e]:(e-E);
  d=min(max(d,0),N-1);
  atomicAdd(&deg[d],1);
}

__global__ void k_scan(const int* __restrict__ deg, int* __restrict__ rs,
                       int* __restrict__ counter, int n,
                       const int* __restrict__ aidx, int* __restrict__ ainv, int na){
  __shared__ int tmp[TPB];
  __shared__ int base;
  int i=blockIdx.x*TPB+threadIdx.x;
  if(i<na){ int a=aidx[i]; if(a>=0&&a<n) ainv[a]=i; }
  int v=(i<n)?deg[i]:0;
  tmp[threadIdx.x]=v; __syncthreads();
  for(int off=1;off<TPB;off<<=1){
    int t=(threadIdx.x>=off)?tmp[threadIdx.x-off]:0;
    __syncthreads();
    tmp[threadIdx.x]+=t;
    __syncthreads();
  }
  if(threadIdx.x==TPB-1) base=atomicAdd(counter,tmp[TPB-1]);
  __syncthreads();
  if(i<n) rs[i]=base+tmp[threadIdx.x]-v;
}

__global__ void k_fill(const int* __restrict__ src, const int* __restrict__ dst, int E, int N,
                       const int* __restrict__ rs, int* __restrict__ fill, int* __restrict__ col){
  int e=blockIdx.x*blockDim.x+threadIdx.x; if(e>=E+N) return;
  int d,s;
  if(e<E){ d=dst[e]; s=src[e]; } else { d=e-E; s=e-E; }
  d=min(max(d,0),N-1); s=min(max(s,0),N-1);
  int p=rs[d]+atomicAdd(&fill[d],1);
  col[p]=s;
}

// ---------------- W[256,256] -> WT = W^T as bf16 (z selects which weight) ----------------
__global__ __launch_bounds__(256) void k_trans(const void* __restrict__ Wa, u16* __restrict__ WTa,
                                               const void* __restrict__ Wb, u16* __restrict__ WTb,
                                               const int* __restrict__ flag){
  __shared__ float s[64][65];
  const void* W = blockIdx.z ? Wb : Wa;
  u16* WT = blockIdx.z ? WTb : WTa;
  const int isbf=flag[0];
  int tx=threadIdx.x&63, ty=threadIdx.x>>6;
  int k0=blockIdx.x*64, n0=blockIdx.y*64;
  #pragma unroll
  for(int i=0;i<64;i+=4)
    s[ty+i][tx]=ld1(W,(size_t)(k0+ty+i)*256+n0+tx,isbf);
  __syncthreads();
  #pragma unroll
  for(int i=0;i<64;i+=4)
    WT[(size_t)(n0+ty+i)*256+k0+tx]=f2b(s[tx][ty+i]);
}

// ---------------- MFMA GEMM: C[M,256] = A[M,256] @ B, A bf16, BT = B^T bf16 ----------------
__global__ __launch_bounds__(256) void k_gemm(const u16* __restrict__ A, const u16* __restrict__ BT,
                                              u16* __restrict__ C, int M){
  __shared__ short As[128*32];
  __shared__ short Bs[128*32];
  const int t=threadIdx.x;
  const int lane=t&63, wv=t>>6;
  const int wm=wv>>1, wn=wv&1;
  const int m15=lane&15, kg=lane>>4;
  const int gm0=blockIdx.x*128, n0=blockIdx.y*128;
  int r0=wv*32+(lane>>2), r1=r0+16;
  int slot=lane&3;
  int kq0=slot^((r0>>1)&3), kq1=slot^((r1>>1)&3);
  int ga0=gm0+r0; ga0=ga0<M?ga0:M-1;
  int ga1=gm0+r1; ga1=ga1<M?ga1:M-1;
  const u16* ap0=A+(size_t)ga0*256+kq0*8;
  const u16* ap1=A+(size_t)ga1*256+kq1*8;
  const u16* bp0=BT+(size_t)(n0+r0)*256+kq0*8;
  const u16* bp1=BT+(size_t)(n0+r1)*256+kq1*8;
  short* al0=As+(wv*32)*32;
  short* al1=As+(wv*32+16)*32;
  short* bl0=Bs+(wv*32)*32;
  short* bl1=Bs+(wv*32+16)*32;
  f32x4 acc[4][4]={};
  for(int k0=0;k0<256;k0+=32){
    GLDS16(ap0+k0,al0); GLDS16(ap1+k0,al1);
    GLDS16(bp0+k0,bl0); GLDS16(bp1+k0,bl1);
    __syncthreads();
    short8 af[4], bf[4];
    #pragma unroll
    for(int mi=0;mi<4;++mi){
      int row=wm*64+mi*16+m15;
      af[mi]=*(const short8*)&As[row*32+((kg^((row>>1)&3)))*8];
    }
    #pragma unroll
    for(int ni=0;ni<4;++ni){
      int row=wn*64+ni*16+m15;
      bf[ni]=*(const short8*)&Bs[row*32+((kg^((row>>1)&3)))*8];
    }
    #pragma unroll
    for(int mi=0;mi<4;++mi)
      #pragma unroll
      for(int ni=0;ni<4;++ni)
        acc[mi][ni]=__builtin_amdgcn_mfma_f32_16x16x32_bf16(af[mi],bf[ni],acc[mi][ni],0,0,0);
    __syncthreads();
  }
  #pragma unroll
  for(int mi=0;mi<4;++mi){
    #pragma unroll
    for(int r=0;r<4;++r){
      int grow=gm0+wm*64+mi*16+kg*4+r;
      if(grow<M){
        #pragma unroll
        for(int ni=0;ni<4;++ni){
          int gcol=n0+wn*64+ni*16+m15;
          C[(size_t)grow*256+gcol]=f2b(acc[mi][ni][r]);
        }
      }
    }
  }
}

// ---------------- attention logits per node + int8(per-row scale) copy of xl ----------------
// asv[node] = {a_src_head0, a_src_head1, row_scale, 0}; adv[node] = {a_dst0, a_dst1}.
__global__ __launch_bounds__(256) void k_att(const u16* __restrict__ xl, const void* __restrict__ as_,
                                             const void* __restrict__ ad_, float4* __restrict__ asv,
                                             float2* __restrict__ adv, u8* __restrict__ xl8,
                                             int n, const int* __restrict__ flag){
  const int isbf=flag[0];
  int w=(blockIdx.x*256+threadIdx.x)>>6;
  int lane=threadIdx.x&63;
  if(w>=n) return;
  int ch=lane*4;
  ushort4 u=*(const ushort4*)(xl+(size_t)w*256+ch);
  float4 s=ld4(as_,ch>>2,isbf);
  float4 d=ld4(ad_,ch>>2,isbf);
  float x0=b2f(u.x),x1=b2f(u.y),x2=b2f(u.z),x3=b2f(u.w);
  // row absmax over all 64 lanes
  float m=fmaxf(fmaxf(fabsf(x0),fabsf(x1)),fmaxf(fabsf(x2),fabsf(x3)));
  for(int off=32;off;off>>=1) m=fmaxf(m,__shfl_xor(m,off));
  float mm=fmaxf(m,1e-20f);
  float scale=mm*(1.f/127.f);
  float rsc=127.f/mm;
  int q0=(int)rintf(fmaf(x0,rsc,128.f));
  int q1=(int)rintf(fmaf(x1,rsc,128.f));
  int q2=(int)rintf(fmaf(x2,rsc,128.f));
  int q3=(int)rintf(fmaf(x3,rsc,128.f));
  u32 pack=(u32)q0|((u32)q1<<8)|((u32)q2<<16)|((u32)q3<<24);
  ((u32*)(xl8+(size_t)w*256))[lane]=pack;
  float ps=x0*s.x+x1*s.y+x2*s.z+x3*s.w;
  float pd=x0*d.x+x1*d.y+x2*d.z+x3*d.w;
  for(int off=16;off;off>>=1){ ps+=__shfl_xor(ps,off); pd+=__shfl_xor(pd,off); }
  float ps1=__shfl(ps,32), pd1=__shfl(pd,32);
  if(lane==0){
    asv[w]=make_float4(ps,ps1,scale,0.f);
    adv[w]=make_float2(pd,pd1);
  }
}

// ---------------- per-edge softmax weights (edge-per-lane) + per-dst denominators ----------------
// ew[slot] = int2{ src_node, half2(w0*scale_src, w1*scale_src) } -> one 8B load/edge in k_agg,
// source-row dequant scale folded into the weight. Denominators use exact unscaled f32 sums.
__global__ __launch_bounds__(256) void k_alpha(const int* __restrict__ rs, const int* __restrict__ deg,
    const int* __restrict__ col, const float4* __restrict__ asv, const float2* __restrict__ adv,
    int2* __restrict__ ew, float2* __restrict__ rden, int n){
  int w=(blockIdx.x*256+threadIdx.x)>>6;
  int lane=threadIdx.x&63;
  if(w>=n) return;
  int s0=rs[w], cnt=deg[w];
  float2 ad=adv[w];
  float sum0=0.f, sum1=0.f;
  for(int base=0;base<cnt;base+=64){
    int j=base+lane;
    if(j<cnt){
      int sv=col[s0+j];
      float4 a=asv[sv];
      float e0=fminf(lrelu(a.x+ad.x),11.f);   // clamp: keep exp finite in f16
      float e1=fminf(lrelu(a.y+ad.y),11.f);
      float w0=__expf(e0), w1=__expf(e1);
      sum0+=w0; sum1+=w1;
      __half2 p=__floats2half2_rn(w0*a.z,w1*a.z);
      ew[s0+j]=make_int2(sv,*(int*)&p);
    }
  }
  for(int off=32;off;off>>=1){ sum0+=__shfl_xor(sum0,off); sum1+=__shfl_xor(sum1,off); }
  if(lane==0) rden[w]=make_float2(1.f/(sum0+1e-16f),1.f/(sum1+1e-16f));
}

// ---------------- weighted aggregation: wave per dst, int8 row gather ----------------
// numerator_c = sum(wbs*q_c) - 128*sum(wbs), wbs = w*scale_src (pre-folded).
__global__ __launch_bounds__(256) void k_agg(const int* __restrict__ rs, const int* __restrict__ deg,
    const int2* __restrict__ ew, const float2* __restrict__ rden,
    const u8* __restrict__ xl8, const void* __restrict__ bias,
    u16* __restrict__ hout, void* __restrict__ out, int ostride, int ocol,
    const int* __restrict__ ainv, int n, const int* __restrict__ flag){
  const int isbf=flag[0];
  int w=(blockIdx.x*blockDim.x+threadIdx.x)>>6;
  int lane=threadIdx.x&63;
  if(w>=n) return;
  int s0=rs[w], cnt=deg[w];
  int ch=lane*4, h=ch>>7;
  float4 acc=make_float4(0.f,0.f,0.f,0.f);
  float sumw=0.f;
  int j=0;
  for(; j+8<=cnt; j+=8){
    int2 e[8];
    #pragma unroll
    for(int u=0;u<8;++u) e[u]=ew[s0+j+u];
    u32 rv[8];
    #pragma unroll
    for(int u=0;u<8;++u) rv[u]=((const u32*)(xl8+(size_t)e[u].x*256))[lane];
    #pragma unroll
    for(int u=0;u<8;++u){
      __half2 p=*(__half2*)&e[u].y;
      float wb=__half2float(h?__high2half(p):__low2half(p));
      float f0=(float)(rv[u]&0xffu);
      float f1=(float)((rv[u]>>8)&0xffu);
      float f2=(float)((rv[u]>>16)&0xffu);
      float f3=(float)(rv[u]>>24);
      acc.x=fmaf(wb,f0,acc.x); acc.y=fmaf(wb,f1,acc.y);
      acc.z=fmaf(wb,f2,acc.z); acc.w=fmaf(wb,f3,acc.w);
      sumw+=wb;
    }
  }
  for(; j<cnt; ++j){
    int2 e=ew[s0+j];
    u32 rv=((const u32*)(xl8+(size_t)e.x*256))[lane];
    __half2 p=*(__half2*)&e.y;
    float wb=__half2float(h?__high2half(p):__low2half(p));
    float f0=(float)(rv&0xffu);
    float f1=(float)((rv>>8)&0xffu);
    float f2=(float)((rv>>16)&0xffu);
    float f3=(float)(rv>>24);
    acc.x=fmaf(wb,f0,acc.x); acc.y=fmaf(wb,f1,acc.y);
    acc.z=fmaf(wb,f2,acc.z); acc.w=fmaf(wb,f3,acc.w);
    sumw+=wb;
  }
  float2 rd=rden[w];
  float rh=h?rd.y:rd.x;
  float4 bv=ld4(bias,ch>>2,isbf);
  float c=128.f*sumw;
  float r0=sigm((acc.x-c)*rh+bv.x);
  float r1=sigm((acc.y-c)*rh+bv.y);
  float r2=sigm((acc.z-c)*rh+bv.z);
  float r3=sigm((acc.w-c)*rh+bv.w);
  if(hout){
    ushort4 ov; ov.x=f2b(r0); ov.y=f2b(r1); ov.z=f2b(r2); ov.w=f2b(r3);
    *(ushort4*)(hout+(size_t)w*256+ch)=ov;
  }
  int ar=ainv[w];
  if(ar>=0){
    size_t o=(size_t)ar*ostride+ocol+ch;
    if(isbf){
      ushort4 ov; ov.x=f2b(r0); ov.y=f2b(r1); ov.z=f2b(r2); ov.w=f2b(r3);
      *(ushort4*)((u16*)out+o)=ov;
    }else{
      *(float4*)((float*)out+o)=make_float4(r0,r1,r2,r3);
    }
  }
}

extern "C" void kernel_launch(void* const* d_in, const int* in_sizes, int n_in,
                              void* d_out, int out_size, void* d_ws, size_t ws_size,
                              hipStream_t stream) {
  const void* x   = d_in[0];
  const int*  ei  = (const int*)d_in[1];
  const int*  aidx= (const int*)d_in[3];
  const void* W0  = d_in[4];
  const void* as0 = d_in[5];
  const void* ad0 = d_in[6];
  const void* b0  = d_in[7];
  const void* W1  = d_in[8];
  const void* as1 = d_in[9];
  const void* ad1 = d_in[10];
  const void* b1  = d_in[11];

  const int N  = in_sizes[0]/256;
  const int E  = in_sizes[1]/2;
  const int na = in_sizes[3];
  const int Et = E+N;

  char* ws=(char*)d_ws; size_t off=0;
  auto alloc=[&](size_t bytes)->void*{ void* p=ws+off; off+=(bytes+255)&~(size_t)255; return p; };
  int*   flg =(int*) alloc(256);
  u16*   xl  =(u16*) alloc((size_t)N*256*2);
  u16*   h1  =(u16*) alloc((size_t)N*256*2);   // doubles as xb (x in bf16): dead before k_agg writes h1
  u8*    xl8 =(u8*)  alloc((size_t)N*256);
  u16*   WT0 =(u16*) alloc((size_t)256*256*2);
  u16*   WT1 =(u16*) alloc((size_t)256*256*2);
  float4* asv=(float4*)alloc((size_t)N*16);
  float2* adv=(float2*)alloc((size_t)N*8);
  char*  zbase=ws+off;
  int*   deg =(int*) alloc((size_t)N*4);
  int*   fill=(int*) alloc((size_t)N*4);
  int*   ctr =(int*) alloc(256);
  size_t zlen=(ws+off)-zbase;
  int*   rstp=(int*) alloc((size_t)N*4);
  int*   ainv=(int*) alloc((size_t)N*4);
  int*   col =(int*) alloc((size_t)Et*4);
  int2*  ew  =(int2*)alloc((size_t)Et*8);
  float2* rdn=(float2*)alloc((size_t)N*8);

  u16* xb = h1;   // alias (see above)

  const int* esrc=ei;
  const int* edst=ei+E;

  hipMemsetAsync(zbase,0,zlen,stream);
  hipMemsetAsync(ainv,0xFF,(size_t)N*4,stream);

  k_detect<<<1,256,0,stream>>>((const u16*)W0,flg);
  k_deg  <<<(Et+255)/256,256,0,stream>>>(edst,E,N,deg);
  k_scan <<<(N+TPB-1)/TPB,TPB,0,stream>>>(deg,rstp,ctr,N,aidx,ainv,na);
  k_fill <<<(Et+255)/256,256,0,stream>>>(esrc,edst,E,N,rstp,fill,col);
  k_trans<<<dim3(4,4,2),256,0,stream>>>(W0,WT0,W1,WT1,flg);
  k_x8   <<<(N*32+255)/256,256,0,stream>>>(x,xb,N*32,flg);

  dim3 gg((N+127)/128,2);
  // layer 0
  k_gemm <<<gg,256,0,stream>>>(xb,WT0,xl,N);
  k_att  <<<(N+3)/4,256,0,stream>>>(xl,as0,ad0,asv,adv,xl8,N,flg);
  k_alpha<<<(N+3)/4,256,0,stream>>>(rstp,deg,col,asv,adv,ew,rdn,N);
  k_agg  <<<(N+3)/4,256,0,stream>>>(rstp,deg,ew,rdn,xl8,b0,h1,d_out,512,0,ainv,N,flg);
  // layer 1
  k_gemm <<<gg,256,0,stream>>>(h1,WT1,xl,N);
  k_att  <<<(N+3)/4,256,0,stream>>>(xl,as1,ad1,asv,adv,xl8,N,flg);
  k_alpha<<<(N+3)/4,256,0,stream>>>(rstp,deg,col,asv,adv,ew,rdn,N);
  k_agg  <<<(N+3)/4,256,0,stream>>>(rstp,deg,ew,rdn,xl8,b1,(u16*)nullptr,d_out,512,256,ainv,N,flg);
}

// Round 11
// 386.016 us; speedup vs baseline: 1.1485x; 1.0235x over previous
//
#include <hip/hip_runtime.h>
#include <hip/hip_fp16.h>

typedef unsigned short u16;
typedef unsigned int   u32;
typedef unsigned char  u8;
typedef __attribute__((ext_vector_type(8))) short short8;
typedef __attribute__((ext_vector_type(8))) unsigned short ushort8v;
typedef __attribute__((ext_vector_type(4))) float f32x4;

#define TPB 256

#define GLDS16(g,l) __builtin_amdgcn_global_load_lds( \
    (const __attribute__((address_space(1))) void*)(g), \
    (__attribute__((address_space(3))) void*)(l), 16, 0, 0)

__device__ __forceinline__ float b2f(u16 u){ u32 x=((u32)u)<<16; return __uint_as_float(x); }
__device__ __forceinline__ u16 f2b(float f){ u32 x=__float_as_uint(f); u32 r=x+0x7FFFu+((x>>16)&1u); return (u16)(r>>16); }
__device__ __forceinline__ float lrelu(float x){ return x>0.f?x:0.2f*x; }
__device__ __forceinline__ float sigm(float x){ return 1.f/(1.f+__expf(-x)); }

__device__ __forceinline__ float4 ld4(const void* p, size_t i4, int isbf){
  if(isbf){
    ushort4 u=((const ushort4*)p)[i4];
    return make_float4(b2f(u.x),b2f(u.y),b2f(u.z),b2f(u.w));
  }
  return ((const float4*)p)[i4];
}
__device__ __forceinline__ float ld1(const void* p, size_t i, int isbf){
  return isbf ? b2f(((const u16*)p)[i]) : ((const float*)p)[i];
}

// ---------------- wire-dtype detection (flag=1 -> bf16 wire, 0 -> f32 wire) ----------------
__global__ void k_detect(const u16* __restrict__ w, int* __restrict__ flag){
  __shared__ int s[256];
  int t=threadIdx.x, sane=0;
  for(int i=t;i<512;i+=256){
    u16 u=w[i]; u32 e=(u>>7)&0xFFu;
    if((e>=103u&&e<=143u)||((u&0x7FFFu)==0u)) sane++;
  }
  s[t]=sane; __syncthreads();
  for(int o=128;o;o>>=1){ if(t<o) s[t]+=s[t+o]; __syncthreads(); }
  if(t==0) flag[0]=(s[0]>=480)?1:0;
}

// ---------------- x (wire dtype) -> bf16, 8 elems/thread ----------------
__global__ __launch_bounds__(256) void k_x8(const void* __restrict__ X, u16* __restrict__ xb,
                                            int n8, const int* __restrict__ flag){
  int i=blockIdx.x*256+threadIdx.x; if(i>=n8) return;
  size_t e=(size_t)i*8;
  if(flag[0]){
    *(ushort8v*)(xb+e)=*(const ushort8v*)((const u16*)X+e);
  }else{
    const float4* fp=(const float4*)((const float*)X+e);
    float4 f0=fp[0], f1=fp[1];
    ushort8v o;
    o[0]=f2b(f0.x); o[1]=f2b(f0.y); o[2]=f2b(f0.z); o[3]=f2b(f0.w);
    o[4]=f2b(f1.x); o[5]=f2b(f1.y); o[6]=f2b(f1.z); o[7]=f2b(f1.w);
    *(ushort8v*)(xb+e)=o;
  }
}

// ---------------- graph build ----------------
__global__ void k_deg(const int* __restrict__ dst, int E, int N, int* __restrict__ deg){
  int e=blockIdx.x*blockDim.x+threadIdx.x; if(e>=E+N) return;
  int d=(e<E)?dst[e]:(e-E);
  d=min(max(d,0),N-1);
  atomicAdd(&deg[d],1);
}

__global__ void k_scan(const int* __restrict__ deg, int* __restrict__ rs,
                       int* __restrict__ counter, int n,
                       const int* __restrict__ aidx, int* __restrict__ ainv, int na){
  __shared__ int tmp[TPB];
  __shared__ int base;
  int i=blockIdx.x*TPB+threadIdx.x;
  if(i<na){ int a=aidx[i]; if(a>=0&&a<n) ainv[a]=i; }
  int v=(i<n)?deg[i]:0;
  tmp[threadIdx.x]=v; __syncthreads();
  for(int off=1;off<TPB;off<<=1){
    int t=(threadIdx.x>=off)?tmp[threadIdx.x-off]:0;
    __syncthreads();
    tmp[threadIdx.x]+=t;
    __syncthreads();
  }
  if(threadIdx.x==TPB-1) base=atomicAdd(counter,tmp[TPB-1]);
  __syncthreads();
  if(i<n) rs[i]=base+tmp[threadIdx.x]-v;
}

__global__ void k_fill(const int* __restrict__ src, const int* __restrict__ dst, int E, int N,
                       const int* __restrict__ rs, int* __restrict__ fill, int* __restrict__ col){
  int e=blockIdx.x*blockDim.x+threadIdx.x; if(e>=E+N) return;
  int d,s;
  if(e<E){ d=dst[e]; s=src[e]; } else { d=e-E; s=e-E; }
  d=min(max(d,0),N-1); s=min(max(s,0),N-1);
  int p=rs[d]+atomicAdd(&fill[d],1);
  col[p]=s;
}

// ---------------- W[256,256] -> WT = W^T as bf16 (z selects which weight) ----------------
__global__ __launch_bounds__(256) void k_trans(const void* __restrict__ Wa, u16* __restrict__ WTa,
                                               const void* __restrict__ Wb, u16* __restrict__ WTb,
                                               const int* __restrict__ flag){
  __shared__ float s[64][65];
  const void* W = blockIdx.z ? Wb : Wa;
  u16* WT = blockIdx.z ? WTb : WTa;
  const int isbf=flag[0];
  int tx=threadIdx.x&63, ty=threadIdx.x>>6;
  int k0=blockIdx.x*64, n0=blockIdx.y*64;
  #pragma unroll
  for(int i=0;i<64;i+=4)
    s[ty+i][tx]=ld1(W,(size_t)(k0+ty+i)*256+n0+tx,isbf);
  __syncthreads();
  #pragma unroll
  for(int i=0;i<64;i+=4)
    WT[(size_t)(n0+ty+i)*256+k0+tx]=f2b(s[tx][ty+i]);
}

// ---------------- MFMA GEMM: C[M,256] = A[M,256] @ B, A bf16, BT = B^T bf16 ----------------
__global__ __launch_bounds__(256) void k_gemm(const u16* __restrict__ A, const u16* __restrict__ BT,
                                              u16* __restrict__ C, int M){
  __shared__ short As[128*32];
  __shared__ short Bs[128*32];
  const int t=threadIdx.x;
  const int lane=t&63, wv=t>>6;
  const int wm=wv>>1, wn=wv&1;
  const int m15=lane&15, kg=lane>>4;
  const int gm0=blockIdx.x*128, n0=blockIdx.y*128;
  int r0=wv*32+(lane>>2), r1=r0+16;
  int slot=lane&3;
  int kq0=slot^((r0>>1)&3), kq1=slot^((r1>>1)&3);
  int ga0=gm0+r0; ga0=ga0<M?ga0:M-1;
  int ga1=gm0+r1; ga1=ga1<M?ga1:M-1;
  const u16* ap0=A+(size_t)ga0*256+kq0*8;
  const u16* ap1=A+(size_t)ga1*256+kq1*8;
  const u16* bp0=BT+(size_t)(n0+r0)*256+kq0*8;
  const u16* bp1=BT+(size_t)(n0+r1)*256+kq1*8;
  short* al0=As+(wv*32)*32;
  short* al1=As+(wv*32+16)*32;
  short* bl0=Bs+(wv*32)*32;
  short* bl1=Bs+(wv*32+16)*32;
  f32x4 acc[4][4]={};
  for(int k0=0;k0<256;k0+=32){
    GLDS16(ap0+k0,al0); GLDS16(ap1+k0,al1);
    GLDS16(bp0+k0,bl0); GLDS16(bp1+k0,bl1);
    __syncthreads();
    short8 af[4], bf[4];
    #pragma unroll
    for(int mi=0;mi<4;++mi){
      int row=wm*64+mi*16+m15;
      af[mi]=*(const short8*)&As[row*32+((kg^((row>>1)&3)))*8];
    }
    #pragma unroll
    for(int ni=0;ni<4;++ni){
      int row=wn*64+ni*16+m15;
      bf[ni]=*(const short8*)&Bs[row*32+((kg^((row>>1)&3)))*8];
    }
    #pragma unroll
    for(int mi=0;mi<4;++mi)
      #pragma unroll
      for(int ni=0;ni<4;++ni)
        acc[mi][ni]=__builtin_amdgcn_mfma_f32_16x16x32_bf16(af[mi],bf[ni],acc[mi][ni],0,0,0);
    __syncthreads();
  }
  #pragma unroll
  for(int mi=0;mi<4;++mi){
    #pragma unroll
    for(int r=0;r<4;++r){
      int grow=gm0+wm*64+mi*16+kg*4+r;
      if(grow<M){
        #pragma unroll
        for(int ni=0;ni<4;++ni){
          int gcol=n0+wn*64+ni*16+m15;
          C[(size_t)grow*256+gcol]=f2b(acc[mi][ni][r]);
        }
      }
    }
  }
}

// ---------------- attention logits per node + int8(per-row scale) copy of xl ----------------
// asv[node] = {a_src_head0, a_src_head1, row_scale, 0}; adv[node] = {a_dst0, a_dst1}.
__global__ __launch_bounds__(256) void k_att(const u16* __restrict__ xl, const void* __restrict__ as_,
                                             const void* __restrict__ ad_, float4* __restrict__ asv,
                                             float2* __restrict__ adv, u8* __restrict__ xl8,
                                             int n, const int* __restrict__ flag){
  const int isbf=flag[0];
  int w=(blockIdx.x*256+threadIdx.x)>>6;
  int lane=threadIdx.x&63;
  if(w>=n) return;
  int ch=lane*4;
  ushort4 u=*(const ushort4*)(xl+(size_t)w*256+ch);
  float4 s=ld4(as_,ch>>2,isbf);
  float4 d=ld4(ad_,ch>>2,isbf);
  float x0=b2f(u.x),x1=b2f(u.y),x2=b2f(u.z),x3=b2f(u.w);
  // row absmax over all 64 lanes
  float m=fmaxf(fmaxf(fabsf(x0),fabsf(x1)),fmaxf(fabsf(x2),fabsf(x3)));
  for(int off=32;off;off>>=1) m=fmaxf(m,__shfl_xor(m,off));
  float mm=fmaxf(m,1e-20f);
  float scale=mm*(1.f/127.f);
  float rsc=127.f/mm;
  int q0=(int)rintf(fmaf(x0,rsc,128.f));
  int q1=(int)rintf(fmaf(x1,rsc,128.f));
  int q2=(int)rintf(fmaf(x2,rsc,128.f));
  int q3=(int)rintf(fmaf(x3,rsc,128.f));
  u32 pack=(u32)q0|((u32)q1<<8)|((u32)q2<<16)|((u32)q3<<24);
  ((u32*)(xl8+(size_t)w*256))[lane]=pack;
  float ps=x0*s.x+x1*s.y+x2*s.z+x3*s.w;
  float pd=x0*d.x+x1*d.y+x2*d.z+x3*d.w;
  for(int off=16;off;off>>=1){ ps+=__shfl_xor(ps,off); pd+=__shfl_xor(pd,off); }
  float ps1=__shfl(ps,32), pd1=__shfl(pd,32);
  if(lane==0){
    asv[w]=make_float4(ps,ps1,scale,0.f);
    adv[w]=make_float2(pd,pd1);
  }
}

// ---------------- per-edge softmax weights (edge-per-lane) + per-dst denominators ----------------
__global__ __launch_bounds__(256) void k_alpha(const int* __restrict__ rs, const int* __restrict__ deg,
    const int* __restrict__ col, const float4* __restrict__ asv, const float2* __restrict__ adv,
    int2* __restrict__ ew, float2* __restrict__ rden, int n){
  int w=(blockIdx.x*256+threadIdx.x)>>6;
  int lane=threadIdx.x&63;
  if(w>=n) return;
  int s0=rs[w], cnt=deg[w];
  float2 ad=adv[w];
  float sum0=0.f, sum1=0.f;
  for(int base=0;base<cnt;base+=64){
    int j=base+lane;
    if(j<cnt){
      int sv=col[s0+j];
      float4 a=asv[sv];
      float e0=fminf(lrelu(a.x+ad.x),11.f);   // clamp: keep exp finite in f16
      float e1=fminf(lrelu(a.y+ad.y),11.f);
      float w0=__expf(e0), w1=__expf(e1);
      sum0+=w0; sum1+=w1;
      __half2 p=__floats2half2_rn(w0*a.z,w1*a.z);
      ew[s0+j]=make_int2(sv,*(int*)&p);
    }
  }
  for(int off=32;off;off>>=1){ sum0+=__shfl_xor(sum0,off); sum1+=__shfl_xor(sum1,off); }
  if(lane==0) rden[w]=make_float2(1.f/(sum0+1e-16f),1.f/(sum1+1e-16f));
}

// ---------------- weighted aggregation: HALF-WAVE per dst, int8 row gather ----------------
// 32 lanes x 8B (dwordx2) cover one 256B row -> one wave-level vmem instr serves
// 2 edges (one per half). No cross-lane merges (halves own distinct dsts).
// Tail edges clamp index to cnt-1 with weight 0 (L1-hit re-read, no padding row).
__global__ __launch_bounds__(256) void k_agg(const int* __restrict__ rs, const int* __restrict__ deg,
    const int2* __restrict__ ew, const float2* __restrict__ rden,
    const u8* __restrict__ xl8, const void* __restrict__ bias,
    u16* __restrict__ hout, void* __restrict__ out, int ostride, int ocol,
    const int* __restrict__ ainv, int n, const int* __restrict__ flag){
  const int isbf=flag[0];
  int w=(blockIdx.x*blockDim.x+threadIdx.x)>>5;   // one 32-lane half-wave per dst
  int sl=threadIdx.x&31;
  if(w>=n) return;
  int s0=rs[w], cnt=deg[w];
  int ch=sl*8, h=sl>>4;     // 8 channels/lane; head = ch>>7
  float acc[8]={};
  float sumw=0.f;
  for(int j=0;j<cnt;j+=4){
    int2 e[4];
    #pragma unroll
    for(int u=0;u<4;++u){
      int idx=j+u; idx=idx<cnt?idx:cnt-1;
      e[u]=ew[s0+idx];
    }
    uint2 rv[4];
    #pragma unroll
    for(int u=0;u<4;++u)
      rv[u]=*(const uint2*)(xl8+(size_t)e[u].x*256+ch);
    #pragma unroll
    for(int u=0;u<4;++u){
      __half2 p=*(__half2*)&e[u].y;
      float wb=__half2float(h?__high2half(p):__low2half(p));
      wb=(j+u<cnt)?wb:0.f;
      u32 a=rv[u].x, b=rv[u].y;
      acc[0]=fmaf(wb,(float)( a     &255u),acc[0]);
      acc[1]=fmaf(wb,(float)((a>> 8)&255u),acc[1]);
      acc[2]=fmaf(wb,(float)((a>>16)&255u),acc[2]);
      acc[3]=fmaf(wb,(float)( a>>24      ),acc[3]);
      acc[4]=fmaf(wb,(float)( b     &255u),acc[4]);
      acc[5]=fmaf(wb,(float)((b>> 8)&255u),acc[5]);
      acc[6]=fmaf(wb,(float)((b>>16)&255u),acc[6]);
      acc[7]=fmaf(wb,(float)( b>>24      ),acc[7]);
      sumw+=wb;
    }
  }
  float2 rd=rden[w];
  float rh=h?rd.y:rd.x;
  float4 b0=ld4(bias,ch>>2,isbf);
  float4 b1=ld4(bias,(ch>>2)+1,isbf);
  float c=128.f*sumw;
  float r[8];
  r[0]=sigm((acc[0]-c)*rh+b0.x); r[1]=sigm((acc[1]-c)*rh+b0.y);
  r[2]=sigm((acc[2]-c)*rh+b0.z); r[3]=sigm((acc[3]-c)*rh+b0.w);
  r[4]=sigm((acc[4]-c)*rh+b1.x); r[5]=sigm((acc[5]-c)*rh+b1.y);
  r[6]=sigm((acc[6]-c)*rh+b1.z); r[7]=sigm((acc[7]-c)*rh+b1.w);
  ushort8v ov;
  #pragma unroll
  for(int q=0;q<8;++q) ov[q]=f2b(r[q]);
  if(hout) *(ushort8v*)(hout+(size_t)w*256+ch)=ov;
  int ar=ainv[w];
  if(ar>=0){
    size_t o=(size_t)ar*ostride+ocol+ch;
    if(isbf){
      *(ushort8v*)((u16*)out+o)=ov;
    }else{
      *(float4*)((float*)out+o)  =make_float4(r[0],r[1],r[2],r[3]);
      *(float4*)((float*)out+o+4)=make_float4(r[4],r[5],r[6],r[7]);
    }
  }
}

extern "C" void kernel_launch(void* const* d_in, const int* in_sizes, int n_in,
                              void* d_out, int out_size, void* d_ws, size_t ws_size,
                              hipStream_t stream) {
  const void* x   = d_in[0];
  const int*  ei  = (const int*)d_in[1];
  const int*  aidx= (const int*)d_in[3];
  const void* W0  = d_in[4];
  const void* as0 = d_in[5];
  const void* ad0 = d_in[6];
  const void* b0  = d_in[7];
  const void* W1  = d_in[8];
  const void* as1 = d_in[9];
  const void* ad1 = d_in[10];
  const void* b1  = d_in[11];

  const int N  = in_sizes[0]/256;
  const int E  = in_sizes[1]/2;
  const int na = in_sizes[3];
  const int Et = E+N;

  char* ws=(char*)d_ws; size_t off=0;
  auto alloc=[&](size_t bytes)->void*{ void* p=ws+off; off+=(bytes+255)&~(size_t)255; return p; };
  int*   flg =(int*) alloc(256);
  u16*   xl  =(u16*) alloc((size_t)N*256*2);
  u16*   h1  =(u16*) alloc((size_t)N*256*2);   // doubles as xb (x in bf16): dead before k_agg writes h1
  u8*    xl8 =(u8*)  alloc((size_t)N*256);
  u16*   WT0 =(u16*) alloc((size_t)256*256*2);
  u16*   WT1 =(u16*) alloc((size_t)256*256*2);
  float4* asv=(float4*)alloc((size_t)N*16);
  float2* adv=(float2*)alloc((size_t)N*8);
  char*  zbase=ws+off;
  int*   deg =(int*) alloc((size_t)N*4);
  int*   fill=(int*) alloc((size_t)N*4);
  int*   ctr =(int*) alloc(256);
  size_t zlen=(ws+off)-zbase;
  int*   rstp=(int*) alloc((size_t)N*4);
  int*   ainv=(int*) alloc((size_t)N*4);
  int*   col =(int*) alloc((size_t)Et*4);
  int2*  ew  =(int2*)alloc((size_t)Et*8);
  float2* rdn=(float2*)alloc((size_t)N*8);

  u16* xb = h1;   // alias (see above)

  const int* esrc=ei;
  const int* edst=ei+E;

  hipMemsetAsync(zbase,0,zlen,stream);
  hipMemsetAsync(ainv,0xFF,(size_t)N*4,stream);

  k_detect<<<1,256,0,stream>>>((const u16*)W0,flg);
  k_deg  <<<(Et+255)/256,256,0,stream>>>(edst,E,N,deg);
  k_scan <<<(N+TPB-1)/TPB,TPB,0,stream>>>(deg,rstp,ctr,N,aidx,ainv,na);
  k_fill <<<(Et+255)/256,256,0,stream>>>(esrc,edst,E,N,rstp,fill,col);
  k_trans<<<dim3(4,4,2),256,0,stream>>>(W0,WT0,W1,WT1,flg);
  k_x8   <<<(N*32+255)/256,256,0,stream>>>(x,xb,N*32,flg);

  dim3 gg((N+127)/128,2);
  // layer 0
  k_gemm <<<gg,256,0,stream>>>(xb,WT0,xl,N);
  k_att  <<<(N+3)/4,256,0,stream>>>(xl,as0,ad0,asv,adv,xl8,N,flg);
  k_alpha<<<(N+3)/4,256,0,stream>>>(rstp,deg,col,asv,adv,ew,rdn,N);
  k_agg  <<<(N+7)/8,256,0,stream>>>(rstp,deg,ew,rdn,xl8,b0,h1,d_out,512,0,ainv,N,flg);
  // layer 1
  k_gemm <<<gg,256,0,stream>>>(h1,WT1,xl,N);
  k_att  <<<(N+3)/4,256,0,stream>>>(xl,as1,ad1,asv,adv,xl8,N,flg);
  k_alpha<<<(N+3)/4,256,0,stream>>>(rstp,deg,col,asv,adv,ew,rdn,N);
  k_agg  <<<(N+7)/8,256,0,stream>>>(rstp,deg,ew,rdn,xl8,b1,(u16*)nullptr,d_out,512,256,ainv,N,flg);
}

// Round 12
// 380.962 us; speedup vs baseline: 1.1637x; 1.0133x over previous
//
#include <hip/hip_runtime.h>
#include <hip/hip_fp16.h>

typedef unsigned short u16;
typedef unsigned int   u32;
typedef unsigned char  u8;
typedef __attribute__((ext_vector_type(8))) short short8;
typedef __attribute__((ext_vector_type(8))) unsigned short ushort8v;
typedef __attribute__((ext_vector_type(4))) float f32x4;

#define TPB 256

#define GLDS16(g,l) __builtin_amdgcn_global_load_lds( \
    (const __attribute__((address_space(1))) void*)(g), \
    (__attribute__((address_space(3))) void*)(l), 16, 0, 0)

__device__ __forceinline__ float b2f(u16 u){ u32 x=((u32)u)<<16; return __uint_as_float(x); }
__device__ __forceinline__ u16 f2b(float f){ u32 x=__float_as_uint(f); u32 r=x+0x7FFFu+((x>>16)&1u); return (u16)(r>>16); }
__device__ __forceinline__ float lrelu(float x){ return x>0.f?x:0.2f*x; }
__device__ __forceinline__ float sigm(float x){ return 1.f/(1.f+__expf(-x)); }

__device__ __forceinline__ float4 ld4(const void* p, size_t i4, int isbf){
  if(isbf){
    ushort4 u=((const ushort4*)p)[i4];
    return make_float4(b2f(u.x),b2f(u.y),b2f(u.z),b2f(u.w));
  }
  return ((const float4*)p)[i4];
}
__device__ __forceinline__ float ld1(const void* p, size_t i, int isbf){
  return isbf ? b2f(((const u16*)p)[i]) : ((const float*)p)[i];
}

// ---------------- graph build (+ wire-dtype detect in block 0, + ainv init) ----------------
__global__ void k_deg(const int* __restrict__ dst, int E, int N, int* __restrict__ deg,
                      int* __restrict__ ainv, const u16* __restrict__ w0, int* __restrict__ flag){
  int gid=blockIdx.x*blockDim.x+threadIdx.x;
  if(blockIdx.x==0){
    __shared__ int s[256];
    int t=threadIdx.x, sane=0;
    for(int i=t;i<512;i+=256){
      u16 u=w0[i]; u32 e=(u>>7)&0xFFu;
      if((e>=103u&&e<=143u)||((u&0x7FFFu)==0u)) sane++;
    }
    s[t]=sane; __syncthreads();
    for(int o=128;o;o>>=1){ if(t<o) s[t]+=s[t+o]; __syncthreads(); }
    if(t==0) flag[0]=(s[0]>=480)?1:0;
  }
  if(gid<N) ainv[gid]=-1;
  if(gid>=E+N) return;
  int d=(gid<E)?dst[gid]:(gid-E);
  d=min(max(d,0),N-1);
  atomicAdd(&deg[d],1);
}

__global__ void k_scan(const int* __restrict__ deg, int* __restrict__ rs,
                       int* __restrict__ counter, int n,
                       const int* __restrict__ aidx, int* __restrict__ ainv, int na){
  __shared__ int tmp[TPB];
  __shared__ int base;
  int i=blockIdx.x*TPB+threadIdx.x;
  if(i<na){ int a=aidx[i]; if(a>=0&&a<n) ainv[a]=i; }
  int v=(i<n)?deg[i]:0;
  tmp[threadIdx.x]=v; __syncthreads();
  for(int off=1;off<TPB;off<<=1){
    int t=(threadIdx.x>=off)?tmp[threadIdx.x-off]:0;
    __syncthreads();
    tmp[threadIdx.x]+=t;
    __syncthreads();
  }
  if(threadIdx.x==TPB-1) base=atomicAdd(counter,tmp[TPB-1]);
  __syncthreads();
  if(i<n) rs[i]=base+tmp[threadIdx.x]-v;
}

__global__ void k_fill(const int* __restrict__ src, const int* __restrict__ dst, int E, int N,
                       const int* __restrict__ rs, int* __restrict__ fill, int* __restrict__ col){
  int e=blockIdx.x*blockDim.x+threadIdx.x; if(e>=E+N) return;
  int d,s;
  if(e<E){ d=dst[e]; s=src[e]; } else { d=e-E; s=e-E; }
  d=min(max(d,0),N-1); s=min(max(s,0),N-1);
  int p=rs[d]+atomicAdd(&fill[d],1);
  col[p]=s;
}

// ---------------- merged: W transpose (blocks 0..31) + x->bf16 (rest) ----------------
__global__ __launch_bounds__(256) void k_prep(const void* __restrict__ Wa, u16* __restrict__ WTa,
                                              const void* __restrict__ Wb, u16* __restrict__ WTb,
                                              const void* __restrict__ X, u16* __restrict__ xb,
                                              int n8, const int* __restrict__ flag){
  const int isbf=flag[0];
  int bid=blockIdx.x;
  if(bid<32){
    __shared__ float s[64][65];
    int z=bid>>4, y=(bid>>2)&3, xb_=bid&3;
    const void* W = z ? Wb : Wa;
    u16* WT = z ? WTb : WTa;
    int tx=threadIdx.x&63, ty=threadIdx.x>>6;
    int k0=xb_*64, n0=y*64;
    #pragma unroll
    for(int i=0;i<64;i+=4)
      s[ty+i][tx]=ld1(W,(size_t)(k0+ty+i)*256+n0+tx,isbf);
    __syncthreads();
    #pragma unroll
    for(int i=0;i<64;i+=4)
      WT[(size_t)(n0+ty+i)*256+k0+tx]=f2b(s[tx][ty+i]);
    return;
  }
  int i=(bid-32)*256+threadIdx.x; if(i>=n8) return;
  size_t e=(size_t)i*8;
  if(isbf){
    *(ushort8v*)(xb+e)=*(const ushort8v*)((const u16*)X+e);
  }else{
    const float4* fp=(const float4*)((const float*)X+e);
    float4 f0=fp[0], f1=fp[1];
    ushort8v o;
    o[0]=f2b(f0.x); o[1]=f2b(f0.y); o[2]=f2b(f0.z); o[3]=f2b(f0.w);
    o[4]=f2b(f1.x); o[5]=f2b(f1.y); o[6]=f2b(f1.z); o[7]=f2b(f1.w);
    *(ushort8v*)(xb+e)=o;
  }
}

// ---------------- MFMA GEMM, BK=64: C[M,256] = A[M,256] @ B, A bf16, BT = B^T bf16 ----------------
// LDS rows are 128B (32 banks); per-row XOR swizzle slot^=(row&7) done on the
// GLOBAL side of global_load_lds (DMA writes stay linear lane*16B), so frag
// ds_read_b128 is <=2-way conflict (free). 4 barrier pairs instead of 8.
__global__ __launch_bounds__(256) void k_gemm(const u16* __restrict__ A, const u16* __restrict__ BT,
                                              u16* __restrict__ C, int M){
  __shared__ short As[128*64];
  __shared__ short Bs[128*64];
  const int t=threadIdx.x;
  const int lane=t&63, wv=t>>6;
  const int wm=wv>>1, wn=wv&1;
  const int m15=lane&15, kg=lane>>4;
  const int gm0=blockIdx.x*128, n0=blockIdx.y*128;
  const int sr=lane>>3, slot=lane&7;
  f32x4 acc[4][4]={};
  for(int k0=0;k0<256;k0+=64){
    #pragma unroll
    for(int i=0;i<4;++i){
      int r=wv*32+i*8+sr;
      int kq=slot^(r&7);
      int ga=gm0+r; ga=ga<M?ga:M-1;
      GLDS16(A+(size_t)ga*256+k0+kq*8, As+(wv*32+i*8)*64);
      GLDS16(BT+(size_t)(n0+r)*256+k0+kq*8, Bs+(wv*32+i*8)*64);
    }
    __syncthreads();
    #pragma unroll
    for(int s=0;s<2;++s){
      short8 af[4], bf[4];
      #pragma unroll
      for(int mi=0;mi<4;++mi){
        int row=wm*64+mi*16+m15;
        int sl=(s*4+kg)^(row&7);
        af[mi]=*(const short8*)&As[row*64+sl*8];
      }
      #pragma unroll
      for(int ni=0;ni<4;++ni){
        int row=wn*64+ni*16+m15;
        int sl=(s*4+kg)^(row&7);
        bf[ni]=*(const short8*)&Bs[row*64+sl*8];
      }
      #pragma unroll
      for(int mi=0;mi<4;++mi)
        #pragma unroll
        for(int ni=0;ni<4;++ni)
          acc[mi][ni]=__builtin_amdgcn_mfma_f32_16x16x32_bf16(af[mi],bf[ni],acc[mi][ni],0,0,0);
    }
    __syncthreads();
  }
  #pragma unroll
  for(int mi=0;mi<4;++mi){
    #pragma unroll
    for(int r=0;r<4;++r){
      int grow=gm0+wm*64+mi*16+kg*4+r;
      if(grow<M){
        #pragma unroll
        for(int ni=0;ni<4;++ni){
          int gcol=n0+wn*64+ni*16+m15;
          C[(size_t)grow*256+gcol]=f2b(acc[mi][ni][r]);
        }
      }
    }
  }
}

// ---------------- attention logits per node + int8(per-row scale) copy of xl ----------------
__global__ __launch_bounds__(256) void k_att(const u16* __restrict__ xl, const void* __restrict__ as_,
                                             const void* __restrict__ ad_, float4* __restrict__ asv,
                                             float2* __restrict__ adv, u8* __restrict__ xl8,
                                             int n, const int* __restrict__ flag){
  const int isbf=flag[0];
  int w=(blockIdx.x*256+threadIdx.x)>>6;
  int lane=threadIdx.x&63;
  if(w>=n) return;
  int ch=lane*4;
  ushort4 u=*(const ushort4*)(xl+(size_t)w*256+ch);
  float4 s=ld4(as_,ch>>2,isbf);
  float4 d=ld4(ad_,ch>>2,isbf);
  float x0=b2f(u.x),x1=b2f(u.y),x2=b2f(u.z),x3=b2f(u.w);
  float m=fmaxf(fmaxf(fabsf(x0),fabsf(x1)),fmaxf(fabsf(x2),fabsf(x3)));
  for(int off=32;off;off>>=1) m=fmaxf(m,__shfl_xor(m,off));
  float mm=fmaxf(m,1e-20f);
  float scale=mm*(1.f/127.f);
  float rsc=127.f/mm;
  int q0=(int)rintf(fmaf(x0,rsc,128.f));
  int q1=(int)rintf(fmaf(x1,rsc,128.f));
  int q2=(int)rintf(fmaf(x2,rsc,128.f));
  int q3=(int)rintf(fmaf(x3,rsc,128.f));
  u32 pack=(u32)q0|((u32)q1<<8)|((u32)q2<<16)|((u32)q3<<24);
  ((u32*)(xl8+(size_t)w*256))[lane]=pack;
  float ps=x0*s.x+x1*s.y+x2*s.z+x3*s.w;
  float pd=x0*d.x+x1*d.y+x2*d.z+x3*d.w;
  for(int off=16;off;off>>=1){ ps+=__shfl_xor(ps,off); pd+=__shfl_xor(pd,off); }
  float ps1=__shfl(ps,32), pd1=__shfl(pd,32);
  if(lane==0){
    asv[w]=make_float4(ps,ps1,scale,0.f);
    adv[w]=make_float2(pd,pd1);
  }
}

// ---------------- per-edge softmax weights (edge-per-lane) + per-dst denominators ----------------
__global__ __launch_bounds__(256) void k_alpha(const int* __restrict__ rs, const int* __restrict__ deg,
    const int* __restrict__ col, const float4* __restrict__ asv, const float2* __restrict__ adv,
    int2* __restrict__ ew, float2* __restrict__ rden, int n){
  int w=(blockIdx.x*256+threadIdx.x)>>6;
  int lane=threadIdx.x&63;
  if(w>=n) return;
  int s0=rs[w], cnt=deg[w];
  float2 ad=adv[w];
  float sum0=0.f, sum1=0.f;
  for(int base=0;base<cnt;base+=64){
    int j=base+lane;
    if(j<cnt){
      int sv=col[s0+j];
      float4 a=asv[sv];
      float e0=fminf(lrelu(a.x+ad.x),11.f);   // clamp: keep exp finite in f16
      float e1=fminf(lrelu(a.y+ad.y),11.f);
      float w0=__expf(e0), w1=__expf(e1);
      sum0+=w0; sum1+=w1;
      __half2 p=__floats2half2_rn(w0*a.z,w1*a.z);
      ew[s0+j]=make_int2(sv,*(int*)&p);
    }
  }
  for(int off=32;off;off>>=1){ sum0+=__shfl_xor(sum0,off); sum1+=__shfl_xor(sum1,off); }
  if(lane==0) rden[w]=make_float2(1.f/(sum0+1e-16f),1.f/(sum1+1e-16f));
}

// ---------------- weighted aggregation: HALF-WAVE per dst, int8 row gather, 8 in flight ----------------
__global__ __launch_bounds__(256) void k_agg(const int* __restrict__ rs, const int* __restrict__ deg,
    const int2* __restrict__ ew, const float2* __restrict__ rden,
    const u8* __restrict__ xl8, const void* __restrict__ bias,
    u16* __restrict__ hout, void* __restrict__ out, int ostride, int ocol,
    const int* __restrict__ ainv, int n, const int* __restrict__ flag){
  const int isbf=flag[0];
  int w=(blockIdx.x*blockDim.x+threadIdx.x)>>5;   // one 32-lane half-wave per dst
  int sl=threadIdx.x&31;
  if(w>=n) return;
  int s0=rs[w], cnt=deg[w];
  int ch=sl*8, h=sl>>4;
  float acc[8]={};
  float sumw=0.f;
  for(int j=0;j<cnt;j+=8){
    int2 e[8];
    #pragma unroll
    for(int u=0;u<8;++u){
      int idx=j+u; idx=idx<cnt?idx:cnt-1;
      e[u]=ew[s0+idx];
    }
    uint2 rv[8];
    #pragma unroll
    for(int u=0;u<8;++u)
      rv[u]=*(const uint2*)(xl8+(size_t)e[u].x*256+ch);
    #pragma unroll
    for(int u=0;u<8;++u){
      __half2 p=*(__half2*)&e[u].y;
      float wb=__half2float(h?__high2half(p):__low2half(p));
      wb=(j+u<cnt)?wb:0.f;
      u32 a=rv[u].x, b=rv[u].y;
      acc[0]=fmaf(wb,(float)( a     &255u),acc[0]);
      acc[1]=fmaf(wb,(float)((a>> 8)&255u),acc[1]);
      acc[2]=fmaf(wb,(float)((a>>16)&255u),acc[2]);
      acc[3]=fmaf(wb,(float)( a>>24      ),acc[3]);
      acc[4]=fmaf(wb,(float)( b     &255u),acc[4]);
      acc[5]=fmaf(wb,(float)((b>> 8)&255u),acc[5]);
      acc[6]=fmaf(wb,(float)((b>>16)&255u),acc[6]);
      acc[7]=fmaf(wb,(float)( b>>24      ),acc[7]);
      sumw+=wb;
    }
  }
  float2 rd=rden[w];
  float rh=h?rd.y:rd.x;
  float4 b0=ld4(bias,ch>>2,isbf);
  float4 b1=ld4(bias,(ch>>2)+1,isbf);
  float c=128.f*sumw;
  float r[8];
  r[0]=sigm((acc[0]-c)*rh+b0.x); r[1]=sigm((acc[1]-c)*rh+b0.y);
  r[2]=sigm((acc[2]-c)*rh+b0.z); r[3]=sigm((acc[3]-c)*rh+b0.w);
  r[4]=sigm((acc[4]-c)*rh+b1.x); r[5]=sigm((acc[5]-c)*rh+b1.y);
  r[6]=sigm((acc[6]-c)*rh+b1.z); r[7]=sigm((acc[7]-c)*rh+b1.w);
  ushort8v ov;
  #pragma unroll
  for(int q=0;q<8;++q) ov[q]=f2b(r[q]);
  if(hout) *(ushort8v*)(hout+(size_t)w*256+ch)=ov;
  int ar=ainv[w];
  if(ar>=0){
    size_t o=(size_t)ar*ostride+ocol+ch;
    if(isbf){
      *(ushort8v*)((u16*)out+o)=ov;
    }else{
      *(float4*)((float*)out+o)  =make_float4(r[0],r[1],r[2],r[3]);
      *(float4*)((float*)out+o+4)=make_float4(r[4],r[5],r[6],r[7]);
    }
  }
}

extern "C" void kernel_launch(void* const* d_in, const int* in_sizes, int n_in,
                              void* d_out, int out_size, void* d_ws, size_t ws_size,
                              hipStream_t stream) {
  const void* x   = d_in[0];
  const int*  ei  = (const int*)d_in[1];
  const int*  aidx= (const int*)d_in[3];
  const void* W0  = d_in[4];
  const void* as0 = d_in[5];
  const void* ad0 = d_in[6];
  const void* b0  = d_in[7];
  const void* W1  = d_in[8];
  const void* as1 = d_in[9];
  const void* ad1 = d_in[10];
  const void* b1  = d_in[11];

  const int N  = in_sizes[0]/256;
  const int E  = in_sizes[1]/2;
  const int na = in_sizes[3];
  const int Et = E+N;

  char* ws=(char*)d_ws; size_t off=0;
  auto alloc=[&](size_t bytes)->void*{ void* p=ws+off; off+=(bytes+255)&~(size_t)255; return p; };
  int*   flg =(int*) alloc(256);
  u16*   xl  =(u16*) alloc((size_t)N*256*2);
  u16*   h1  =(u16*) alloc((size_t)N*256*2);   // doubles as xb (x in bf16): dead before k_agg writes h1
  u8*    xl8 =(u8*)  alloc((size_t)N*256);
  u16*   WT0 =(u16*) alloc((size_t)256*256*2);
  u16*   WT1 =(u16*) alloc((size_t)256*256*2);
  float4* asv=(float4*)alloc((size_t)N*16);
  float2* adv=(float2*)alloc((size_t)N*8);
  char*  zbase=ws+off;
  int*   deg =(int*) alloc((size_t)N*4);
  int*   fill=(int*) alloc((size_t)N*4);
  int*   ctr =(int*) alloc(256);
  size_t zlen=(ws+off)-zbase;
  int*   rstp=(int*) alloc((size_t)N*4);
  int*   ainv=(int*) alloc((size_t)N*4);
  int*   col =(int*) alloc((size_t)Et*4);
  int2*  ew  =(int2*)alloc((size_t)Et*8);
  float2* rdn=(float2*)alloc((size_t)N*8);

  u16* xb = h1;   // alias (see above)

  const int* esrc=ei;
  const int* edst=ei+E;

  hipMemsetAsync(zbase,0,zlen,stream);

  k_deg  <<<(Et+255)/256,256,0,stream>>>(edst,E,N,deg,ainv,(const u16*)W0,flg);
  k_scan <<<(N+TPB-1)/TPB,TPB,0,stream>>>(deg,rstp,ctr,N,aidx,ainv,na);
  k_fill <<<(Et+255)/256,256,0,stream>>>(esrc,edst,E,N,rstp,fill,col);
  k_prep <<<32+(N*32+255)/256,256,0,stream>>>(W0,WT0,W1,WT1,x,xb,N*32,flg);

  dim3 gg((N+127)/128,2);
  // layer 0
  k_gemm <<<gg,256,0,stream>>>(xb,WT0,xl,N);
  k_att  <<<(N+3)/4,256,0,stream>>>(xl,as0,ad0,asv,adv,xl8,N,flg);
  k_alpha<<<(N+3)/4,256,0,stream>>>(rstp,deg,col,asv,adv,ew,rdn,N);
  k_agg  <<<(N+7)/8,256,0,stream>>>(rstp,deg,ew,rdn,xl8,b0,h1,d_out,512,0,ainv,N,flg);
  // layer 1
  k_gemm <<<gg,256,0,stream>>>(h1,WT1,xl,N);
  k_att  <<<(N+3)/4,256,0,stream>>>(xl,as1,ad1,asv,adv,xl8,N,flg);
  k_alpha<<<(N+3)/4,256,0,stream>>>(rstp,deg,col,asv,adv,ew,rdn,N);
  k_agg  <<<(N+7)/8,256,0,stream>>>(rstp,deg,ew,rdn,xl8,b1,(u16*)nullptr,d_out,512,256,ainv,N,flg);
}